// Round 10
// baseline (403.597 us; speedup 1.0000x reference)
//
#include <hip/hip_runtime.h>
#include <math.h>

#define NTHR 512
#define NB 2              // batches per WG (kernel1)
#define NROWSR (NB * 20)  // 40 real rows

using bf8 = __attribute__((ext_vector_type(8))) short;
using f4  = __attribute__((ext_vector_type(4))) float;

// kernel1 LDS pool (bytes). Planar hi/lo bf16: [plane][40][PK].
// Row strides multiple of 16B: PK168->336B, PK136->272B, PK40->80B.
#define H1_OFF 0
#define H1_PK 168        // 40*168*4 = 26880
#define H2_OFF 26880
#define H2_PK 136        // 40*136*4 = 21760 -> end 48640
#define FEAT_OFF 0       // aliases H1 (dead after L2)
#define FEAT_PK 136
#define S1_OFF 26880     // aliases H2 (dead after L3); tail zeros inherited
#define S1_PK 136
#define XS_OFF 26880     // aliases H2 region during P0/P1 only
#define XS_PK 40         // 40*40*4 = 6400
#define POOL1 48640

// ws fragment bases (1KB blocks; each (kb,nt) = 2 blocks hi+lo)
#define L1B 0
#define L2B 20
#define L3B 90
#define A1B 146
#define A2B 202
#define M1B 258
#define M2B 338
#define M3B 408
#define JOINT_F 118784   // float offset of joint[16384][106] in ws

// kernel2 (proven config)
#define K2ROWS 64
#define K2THR 256
#define K2_JT_OFF 0      // 64*136*4 = 34816
#define K2_V1_OFF 34816  // 64*168*4 = 43008 -> end 77824
#define K2_POOL 77824

__device__ __forceinline__ float relu_f(float v) { return fmaxf(v, 0.f); }
__device__ __forceinline__ float us2f(ushort u) {
  return __builtin_bit_cast(float, (uint)u << 16);
}
__device__ __forceinline__ void split_store(float v, ushort* p, int pstride) {
  uint bits = __builtin_bit_cast(uint, v);
  float hf = __builtin_bit_cast(float, bits & 0xffff0000u);
  float lf = v - hf;
  p[0] = (ushort)(bits >> 16);
  p[pstride] = (ushort)(__builtin_bit_cast(uint, lf) >> 16);
}

// ---------------- prep: pack hi/lo bf16 weight B-fragments ----------------
__global__ __launch_bounds__(64) void prep_kernel(
    const float* __restrict__ w1, const float* __restrict__ w2,
    const float* __restrict__ w3, const float* __restrict__ a1,
    const float* __restrict__ a2, const float* __restrict__ m1,
    const float* __restrict__ m2, const float* __restrict__ m3,
    uint4* __restrict__ ws) {
  const int job = blockIdx.x;
  const int lane = threadIdx.x;
  const float* W;
  int K, C, NT, base, kb, nt, i;
  if (job < 10)       { W = w1; K = 13;  C = 150; NT = 10; base = L1B; kb = 0; nt = job; }
  else if (job < 45)  { W = w2; K = 150; C = 100; NT = 7;  base = L2B; i = job - 10;  kb = i / 7;  nt = i % 7; }
  else if (job < 73)  { W = w3; K = 100; C = 100; NT = 7;  base = L3B; i = job - 45;  kb = i / 7;  nt = i % 7; }
  else if (job < 101) { W = a1; K = 100; C = 100; NT = 7;  base = A1B; i = job - 73;  kb = i / 7;  nt = i % 7; }
  else if (job < 129) { W = a2; K = 100; C = 100; NT = 7;  base = A2B; i = job - 101; kb = i / 7;  nt = i % 7; }
  else if (job < 169) { W = m1; K = 106; C = 150; NT = 10; base = M1B; i = job - 129; kb = i / 10; nt = i % 10; }
  else if (job < 204) { W = m2; K = 150; C = 100; NT = 7;  base = M2B; i = job - 169; kb = i / 7;  nt = i % 7; }
  else                { W = m3; K = 100; C = 100; NT = 7;  base = M3B; i = job - 204; kb = i / 7;  nt = i % 7; }
  const int r = lane & 15, g = lane >> 4;
  const int j = nt * 16 + r;
  uint hi[8], lo[8];
  for (int e = 0; e < 8; ++e) {
    int k = kb * 32 + g * 8 + e;
    float v = (k < K && j < C) ? W[k * C + j] : 0.f;
    uint bits = __builtin_bit_cast(uint, v);
    hi[e] = bits >> 16;
    float hf = __builtin_bit_cast(float, bits & 0xffff0000u);
    float lf = v - hf;
    lo[e] = __builtin_bit_cast(uint, lf) >> 16;
  }
  uint4 vh = { hi[0] | (hi[1] << 16), hi[2] | (hi[3] << 16),
               hi[4] | (hi[5] << 16), hi[6] | (hi[7] << 16) };
  uint4 vl = { lo[0] | (lo[1] << 16), lo[2] | (lo[3] << 16),
               lo[4] | (lo[5] << 16), lo[6] | (lo[7] << 16) };
  ws[(size_t)(base + (kb * NT + nt) * 2 + 0) * 64 + lane] = vh;
  ws[(size_t)(base + (kb * NT + nt) * 2 + 1) * 64 + lane] = vl;
}

// ---------------- MFMA dense layer (act-as-A, weights-as-B) ----------------
// D-layout: col = lane&15 (+nt*16), act row = (lane>>4)*4+q (+mt*16).
// MODE: 0 relu->planar, 1 linear->planar, 2 relu+gpart->planar,
//       3 relu + a3-dot fold -> sceL atomics (no store)
// W8: 8 waves; wid&3 picks nt-pair, wid>>2 splits mt {0..1} vs {2..}.
template <int KB, int NT, int C, int MODE, int ROWS, bool W8, int NWAVES>
__device__ __forceinline__ void mfma_layer(
    char* pool, int inOff, int PKin, int outOff, int PKout,
    const bf8* __restrict__ wsB, const float* __restrict__ bias,
    const float* gpartL, float* sceL, const float* __restrict__ a3,
    int lane, int wid) {
  constexpr int NTP = (NT + 1) / 2;
  constexpr int MTL = (ROWS + 15) / 16;
  constexpr int TAIL = ROWS & 15;
  const int r = lane & 15, g = lane >> 4;
  const char* Ain = pool + inOff;
  const int pstr = ROWS * PKin * 2;
  int wlo, mtb, mte;
  if constexpr (W8) {
    wlo = wid & 3;
    const int whi = wid >> 2;
    mtb = whi ? 2 : 0; mte = whi ? MTL : 2;
  } else { wlo = wid; mtb = 0; mte = MTL; }
  for (int p = wlo; p < NTP; p += 4) {
    const int nt0 = 2 * p;
    const bool two = (nt0 + 1 < NT);
    bf8 bh0[KB], bl0[KB], bh1[KB], bl1[KB];
#pragma unroll
    for (int kb = 0; kb < KB; ++kb) {
      bh0[kb] = wsB[((kb * NT + nt0) * 2 + 0) * 64 + lane];
      bl0[kb] = wsB[((kb * NT + nt0) * 2 + 1) * 64 + lane];
      if (two) {
        bh1[kb] = wsB[((kb * NT + nt0 + 1) * 2 + 0) * 64 + lane];
        bl1[kb] = wsB[((kb * NT + nt0 + 1) * 2 + 1) * 64 + lane];
      }
    }
    for (int mt = mtb; mt < mte; ++mt) {
      int rA = mt * 16 + r;
      if constexpr (TAIL != 0) {
        if (mt == MTL - 1 && r >= TAIL) rA = mt * 16 + (r & (TAIL - 1));
      }
      f4 acc0 = {0.f, 0.f, 0.f, 0.f}, acc1 = {0.f, 0.f, 0.f, 0.f};
      const char* aHi = Ain + rA * (PKin * 2) + g * 16;
      const char* aLo = aHi + pstr;
#pragma unroll
      for (int kb = 0; kb < KB; ++kb) {
        bf8 ah = *(const bf8*)(aHi + kb * 64);
        bf8 al = *(const bf8*)(aLo + kb * 64);
        acc0 = __builtin_amdgcn_mfma_f32_16x16x32_bf16(ah, bh0[kb], acc0, 0, 0, 0);
        if (two) acc1 = __builtin_amdgcn_mfma_f32_16x16x32_bf16(ah, bh1[kb], acc1, 0, 0, 0);
        acc0 = __builtin_amdgcn_mfma_f32_16x16x32_bf16(al, bh0[kb], acc0, 0, 0, 0);
        if (two) acc1 = __builtin_amdgcn_mfma_f32_16x16x32_bf16(al, bh1[kb], acc1, 0, 0, 0);
        acc0 = __builtin_amdgcn_mfma_f32_16x16x32_bf16(ah, bl0[kb], acc0, 0, 0, 0);
        if (two) acc1 = __builtin_amdgcn_mfma_f32_16x16x32_bf16(ah, bl1[kb], acc1, 0, 0, 0);
      }
#pragma unroll
      for (int t = 0; t < 2; ++t) {
        if (t && !two) break;
        const int nt = nt0 + t;
        const f4 acc = t ? acc1 : acc0;
        const int col = nt * 16 + r;
        const int rbase = mt * 16 + g * 4;
        const float bcol = (col < C) ? bias[col] : 0.f;
        float gp = 0.f;
        if constexpr (MODE == 2) {
          if (col < C && rbase < ROWS) gp = gpartL[(rbase / 20) * 100 + col];
        }
        float a3c = 0.f;
        if constexpr (MODE == 3) { if (col < C) a3c = a3[col]; }
#pragma unroll
        for (int q = 0; q < 4; ++q) {
          const int orow = rbase + q;
          float v = 0.f;
          if (orow < ROWS && col < C) {
            v = acc[q] + bcol;
            if constexpr (MODE == 2) v += gp;
            if constexpr (MODE != 1) v = fmaxf(v, 0.f);
          }
          if constexpr (MODE == 3) {
            float val = v * a3c;
            val += __shfl_xor(val, 1);
            val += __shfl_xor(val, 2);
            val += __shfl_xor(val, 4);
            val += __shfl_xor(val, 8);
            if (r == 0 && orow < ROWS) atomicAdd(&sceL[orow], val);
          } else {
            if (orow < ROWS) {
              ushort* oHi = (ushort*)(pool + outOff) + orow * PKout + col;
              split_store(v, oHi, ROWS * PKout);
            }
          }
        }
      }
    }
  }
}

// zero cols [112,128) of a planar PK=136 buffer (epilogue covers [C,112))
template <int ROWSZ>
__device__ __forceinline__ void zero_tail136(char* pool, int off, int tid) {
  if (tid < 2 * ROWSZ) {
    int row = tid >> 1, pl = tid & 1;
    uint2* z = (uint2*)((ushort*)(pool + off) + (size_t)pl * ROWSZ * 136 + row * 136 + 112);
#pragma unroll
    for (int u = 0; u < 4; ++u) z[u] = uint2{0, 0};
  }
}

// ---------------- kernel1: 2 batches per 512-thr WG (R3 shape + A3-fold) ----------------
// (512,4): VGPR cap 64 (proven spill-free for this loop). LDS ~50.6KB.
__global__ __launch_bounds__(NTHR, 4) void value_net_kernel(
    const float* __restrict__ state,
    const float* __restrict__ b1, const float* __restrict__ b2,
    const float* __restrict__ b3,
    const float* __restrict__ a1, const float* __restrict__ ab1,
    const float* __restrict__ ab2,
    const float* __restrict__ a3, const float* __restrict__ ab3,
    const uint4* __restrict__ ws, float* __restrict__ jointg) {
  __shared__ char pool[POOL1];
  __shared__ float gsL[200], gpartL[200], sceL[40], swL[40];

  const int tid = threadIdx.x;
  const int lane = tid & 63, wid = tid >> 6;
  const int b0 = blockIdx.x * NB;
  const bf8* wsb = (const bf8*)ws;

  // P0: stage state -> XS planar hi/lo (40 x PK40, cols 13..39 zero); zero sceL
  for (int i = tid; i < 40 * XS_PK; i += NTHR) {
    int row = i / XS_PK, k = i - row * XS_PK;
    float v = (k < 13) ? state[((size_t)b0 * 20 + row) * 13 + k] : 0.f;
    split_store(v, (ushort*)(pool + XS_OFF) + row * XS_PK + k, 40 * XS_PK);
  }
  if (tid < 40) sceL[tid] = 0.f;
  __syncthreads();

  // P1: L1 13->150 relu  XS -> H1 (cols [150,160) zeroed by epilogue)
  mfma_layer<1, 10, 150, 0, NROWSR, true, 8>(
      pool, XS_OFF, XS_PK, H1_OFF, H1_PK, wsb + L1B * 64, b1,
      nullptr, nullptr, nullptr, lane, wid);
  __syncthreads();

  // P2: zero H2 tail; L2 150->100 relu  H1 -> H2
  zero_tail136<NROWSR>(pool, H2_OFF, tid);
  mfma_layer<5, 7, 100, 0, NROWSR, true, 8>(
      pool, H1_OFF, H1_PK, H2_OFF, H2_PK, wsb + L2B * 64, b2,
      nullptr, nullptr, nullptr, lane, wid);
  __syncthreads();

  // P3: zero FEAT tail; L3 100->100 linear  H2 -> FEAT
  zero_tail136<NROWSR>(pool, FEAT_OFF, tid);
  mfma_layer<4, 7, 100, 1, NROWSR, true, 8>(
      pool, H2_OFF, H2_PK, FEAT_OFF, FEAT_PK, wsb + L3B * 64, b3,
      nullptr, nullptr, nullptr, lane, wid);
  __syncthreads();

  // P4: gs = mean over n (x0.05)
  if (tid < NB * 100) {
    const int b = tid / 100, d = tid - b * 100;
    const ushort* fh = (const ushort*)(pool + FEAT_OFF);
    const ushort* fl = fh + NROWSR * FEAT_PK;
    float s = 0.f;
    for (int n = 0; n < 20; ++n) {
      int rw = b * 20 + n;
      s += us2f(fh[rw * FEAT_PK + d]) + us2f(fl[rw * FEAT_PK + d]);
    }
    gsL[b * 100 + d] = s * 0.05f;
  }
  __syncthreads();

  // P5: gpart = gs @ a1[100:200]  (coalesced over j)
  if (tid < 400) {
    const int b = tid / 200, rem = tid - b * 200;
    const int j = rem >> 1, half = rem & 1;
    float acc = 0.f;
    const float* gsb = gsL + b * 100;
    for (int k = half * 50; k < half * 50 + 50; ++k)
      acc += gsb[k] * a1[(100 + k) * 100 + j];
    acc += __shfl_xor(acc, 1);
    if (half == 0) gpartL[b * 100 + j] = acc;
  }
  __syncthreads();

  // P6: A1 (feat half) + gpart, relu  FEAT -> S1 (tail zeros inherited from H2)
  mfma_layer<4, 7, 100, 2, NROWSR, true, 8>(
      pool, FEAT_OFF, FEAT_PK, S1_OFF, S1_PK, wsb + A1B * 64, ab1,
      gpartL, nullptr, nullptr, lane, wid);
  __syncthreads();

  // P7: A2 relu + A3-dot fold -> sceL atomics
  mfma_layer<4, 7, 100, 3, NROWSR, true, 8>(
      pool, S1_OFF, S1_PK, 0, 0, wsb + A2B * 64, ab2,
      nullptr, sceL, a3, lane, wid);
  __syncthreads();

  // P8: softmax over n of relu(score + ab3)
  if (tid < NROWSR) {
    const int b = tid / 20, n = tid - b * 20;
    const float ab3v = ab3[0];
    float m = -1e30f;
    for (int i = 0; i < 20; ++i) m = fmaxf(m, relu_f(sceL[b * 20 + i] + ab3v));
    float sum = 0.f, mine = 0.f;
    for (int i = 0; i < 20; ++i) {
      float e = __expf(relu_f(sceL[b * 20 + i] + ab3v) - m);
      sum += e;
      if (i == n) mine = e;
    }
    swL[tid] = mine / sum;
  }
  __syncthreads();

  // P9: weighted feature + self -> jointg
  if (tid < 400) {
    const int b = tid / 200, rem = tid - b * 200;
    const int d = rem >> 1, half = rem & 1;
    const ushort* fh = (const ushort*)(pool + FEAT_OFF);
    const ushort* fl = fh + NROWSR * FEAT_PK;
    float acc = 0.f;
    for (int n = half * 10; n < half * 10 + 10; ++n) {
      const int rw = b * 20 + n;
      acc += swL[b * 20 + n] * (us2f(fh[rw * FEAT_PK + d]) + us2f(fl[rw * FEAT_PK + d]));
    }
    acc += __shfl_xor(acc, 1);
    if (half == 0) jointg[(size_t)(b0 + b) * 106 + 6 + d] = acc;
  } else if (tid < 412) {
    const int idx = tid - 400, b = idx / 6, i = idx - b * 6;
    jointg[(size_t)(b0 + b) * 106 + i] = state[((size_t)(b0 + b)) * 260 + i];
  }
}

// ---------------- kernel2: M-MLP GEMM over 16384 rows (proven) ----------------
__global__ __launch_bounds__(K2THR) void mlp2_kernel(
    const float* __restrict__ jointg,
    const float* __restrict__ mb1, const float* __restrict__ mb2,
    const float* __restrict__ mb3,
    const float* __restrict__ m4, const float* __restrict__ mb4,
    const uint4* __restrict__ ws, float* __restrict__ out) {
  __shared__ char pool[K2_POOL];
  __shared__ float m4L[100];
  const int tid = threadIdx.x, lane = tid & 63, wid = tid >> 6;
  const size_t r0 = (size_t)blockIdx.x * K2ROWS;
  const bf8* wsb = (const bf8*)ws;

  // stage joint -> planar hi/lo (PK=136, cols 106..135 zero); m4 -> LDS
  for (int i = tid; i < K2ROWS * 136; i += K2THR) {
    int row = i / 136, k = i - row * 136;
    float v = (k < 106) ? jointg[(r0 + row) * 106 + k] : 0.f;
    split_store(v, (ushort*)(pool + K2_JT_OFF) + row * 136 + k, K2ROWS * 136);
  }
  if (tid < 100) m4L[tid] = m4[tid];
  __syncthreads();

  // M1: 106->150 relu (jt PK136 -> v1 PK168)
  mfma_layer<4, 10, 150, 0, K2ROWS, false, 4>(
      pool, K2_JT_OFF, 136, K2_V1_OFF, 168, wsb + M1B * 64, mb1,
      nullptr, nullptr, nullptr, lane, wid);
  __syncthreads();

  // M2: zero v2 tail; 150->100 relu (v1 -> v2 @0 PK136)
  zero_tail136<K2ROWS>(pool, 0, tid);
  mfma_layer<5, 7, 100, 0, K2ROWS, false, 4>(
      pool, K2_V1_OFF, 168, 0, 136, wsb + M2B * 64, mb2,
      nullptr, nullptr, nullptr, lane, wid);
  __syncthreads();

  // M3: 100->100 relu (v2 -> v3 @V1_OFF PK136)
  mfma_layer<4, 7, 100, 0, K2ROWS, false, 4>(
      pool, 0, 136, K2_V1_OFF, 136, wsb + M3B * 64, mb3,
      nullptr, nullptr, nullptr, lane, wid);
  __syncthreads();

  // M4: 100->1
  {
    const int row = tid >> 2, seg = tid & 3;
    const ushort* vh = (const ushort*)(pool + K2_V1_OFF);
    const ushort* vl = vh + K2ROWS * 136;
    float s = 0.f;
    for (int k = seg; k < 100; k += 4)
      s += (us2f(vh[row * 136 + k]) + us2f(vl[row * 136 + k])) * m4L[k];
    s += __shfl_xor(s, 1);
    s += __shfl_xor(s, 2);
    if (seg == 0) out[r0 + row] = s + mb4[0];
  }
}

extern "C" void kernel_launch(void* const* d_in, const int* in_sizes, int n_in,
                              void* d_out, int out_size, void* d_ws, size_t ws_size,
                              hipStream_t stream) {
  const float* state = (const float*)d_in[0];
  const float* w1 = (const float*)d_in[1];
  const float* b1 = (const float*)d_in[2];
  const float* w2 = (const float*)d_in[3];
  const float* b2 = (const float*)d_in[4];
  const float* w3 = (const float*)d_in[5];
  const float* b3 = (const float*)d_in[6];
  const float* a1 = (const float*)d_in[7];
  const float* ab1 = (const float*)d_in[8];
  const float* a2 = (const float*)d_in[9];
  const float* ab2 = (const float*)d_in[10];
  const float* a3 = (const float*)d_in[11];
  const float* ab3 = (const float*)d_in[12];
  const float* m1 = (const float*)d_in[13];
  const float* mb1 = (const float*)d_in[14];
  const float* m2 = (const float*)d_in[15];
  const float* mb2 = (const float*)d_in[16];
  const float* m3 = (const float*)d_in[17];
  const float* mb3 = (const float*)d_in[18];
  const float* m4 = (const float*)d_in[19];
  const float* mb4 = (const float*)d_in[20];
  float* out = (float*)d_out;
  uint4* ws = (uint4*)d_ws;
  float* jointg = (float*)d_ws + JOINT_F;

  prep_kernel<<<232, 64, 0, stream>>>(w1, w2, w3, a1, a2, m1, m2, m3, ws);

  const int B = in_sizes[0] / 260;  // 16384
  value_net_kernel<<<dim3(B / NB), dim3(NTHR), 0, stream>>>(
      state, b1, b2, b3, a1, ab1, ab2, a3, ab3, (const uint4*)ws, jointg);

  mlp2_kernel<<<dim3(B / K2ROWS), dim3(K2THR), 0, stream>>>(
      jointg, mb1, mb2, mb3, m4, mb4, (const uint4*)ws, out);
}

// Round 11
// 268.860 us; speedup vs baseline: 1.5011x; 1.5011x over previous
//
#include <hip/hip_runtime.h>
#include <math.h>

#define NTHR 512
#define NB 4              // batches per WG (kernel1)
#define NROWSR (NB * 20)  // 80 rows = 5 exact M-tiles

typedef _Float16 h8v __attribute__((ext_vector_type(8)));
using f4 = __attribute__((ext_vector_type(4))) float;

// kernel1 LDS pool (bytes). Single-plane f16: [rows][PK], 2B/elem.
// Row strides multiple of 16B: PK168->336B, PK136->272B, PK40->80B.
#define H1_OFF 0
#define H1_PK 168        // 80*168*2 = 26880
#define H2_OFF 26880
#define H2_PK 136        // 80*136*2 = 21760 -> end 48640
#define FEAT_OFF 0       // aliases H1 (dead after L2)
#define FEAT_PK 136
#define S1_OFF 26880     // aliases H2 (dead after L3); [112,128) zeros inherited
#define S1_PK 136
#define XS_OFF 26880     // aliases H2 region during P0/P1 only
#define XS_PK 40         // 80*40*2 = 6400
#define POOL1 48640

// ws fragment bases (1KB blocks; each (kb,nt) = 2 blocks hi+lo)
#define L1B 0
#define L2B 20
#define L3B 90
#define A1B 146
#define A2B 202
#define M1B 258
#define M2B 338
#define M3B 408
#define JOINT_F 118784   // float offset of joint[16384][106] in ws

// kernel2 (f16 single-plane)
#define K2ROWS 64
#define K2THR 256
#define K2_JT_OFF 0      // 64*136*2 = 17408
#define K2_V1_OFF 17408  // 64*168*2 = 21504 -> end 38912
#define K2_POOL 38912

__device__ __forceinline__ float relu_f(float v) { return fmaxf(v, 0.f); }
__device__ __forceinline__ float h2f(ushort u) {
  return (float)__builtin_bit_cast(_Float16, u);
}
__device__ __forceinline__ ushort f2h(float v) {
  return __builtin_bit_cast(ushort, (_Float16)v);
}

// ---------------- prep: pack hi/lo f16 weight B-fragments ----------------
// Frag (kb, nt, plane): lane l holds out-feature j = nt*16 + (l&15),
// k = kb*32 + (l>>4)*8 + e  (16B per lane).
__global__ __launch_bounds__(64) void prep_kernel(
    const float* __restrict__ w1, const float* __restrict__ w2,
    const float* __restrict__ w3, const float* __restrict__ a1,
    const float* __restrict__ a2, const float* __restrict__ m1,
    const float* __restrict__ m2, const float* __restrict__ m3,
    uint4* __restrict__ ws) {
  const int job = blockIdx.x;
  const int lane = threadIdx.x;
  const float* W;
  int K, C, NT, base, kb, nt, i;
  if (job < 10)       { W = w1; K = 13;  C = 150; NT = 10; base = L1B; kb = 0; nt = job; }
  else if (job < 45)  { W = w2; K = 150; C = 100; NT = 7;  base = L2B; i = job - 10;  kb = i / 7;  nt = i % 7; }
  else if (job < 73)  { W = w3; K = 100; C = 100; NT = 7;  base = L3B; i = job - 45;  kb = i / 7;  nt = i % 7; }
  else if (job < 101) { W = a1; K = 100; C = 100; NT = 7;  base = A1B; i = job - 73;  kb = i / 7;  nt = i % 7; }
  else if (job < 129) { W = a2; K = 100; C = 100; NT = 7;  base = A2B; i = job - 101; kb = i / 7;  nt = i % 7; }
  else if (job < 169) { W = m1; K = 106; C = 150; NT = 10; base = M1B; i = job - 129; kb = i / 10; nt = i % 10; }
  else if (job < 204) { W = m2; K = 150; C = 100; NT = 7;  base = M2B; i = job - 169; kb = i / 7;  nt = i % 7; }
  else                { W = m3; K = 100; C = 100; NT = 7;  base = M3B; i = job - 204; kb = i / 7;  nt = i % 7; }
  const int r = lane & 15, g = lane >> 4;
  const int j = nt * 16 + r;
  uint hi[8], lo[8];
  for (int e = 0; e < 8; ++e) {
    int k = kb * 32 + g * 8 + e;
    float v = (k < K && j < C) ? W[k * C + j] : 0.f;
    _Float16 hh = (_Float16)v;
    float hf = (float)hh;
    _Float16 ll = (_Float16)(v - hf);
    hi[e] = (uint)__builtin_bit_cast(ushort, hh);
    lo[e] = (uint)__builtin_bit_cast(ushort, ll);
  }
  uint4 vh = { hi[0] | (hi[1] << 16), hi[2] | (hi[3] << 16),
               hi[4] | (hi[5] << 16), hi[6] | (hi[7] << 16) };
  uint4 vl = { lo[0] | (lo[1] << 16), lo[2] | (lo[3] << 16),
               lo[4] | (lo[5] << 16), lo[6] | (lo[7] << 16) };
  ws[(size_t)(base + (kb * NT + nt) * 2 + 0) * 64 + lane] = vh;
  ws[(size_t)(base + (kb * NT + nt) * 2 + 1) * 64 + lane] = vl;
}

// ---------------- f16 MFMA dense layer (act-as-A single plane, W hi/lo 2-term) ----------------
// D-layout: col = lane&15 (+nt*16), act row = (lane>>4)*4+q (+mt*16).
// MODE: 0 relu->f16, 1 linear->f16, 2 relu+gpart->f16,
//       3 relu + a3-dot fold -> sceL atomics (no store)
// W8 (8 waves, MTL=5): wid&3 picks nt-pair, wid>>2 splits mt {0,1,2} vs {3,4}.
template <int KB, int NT, int C, int MODE, int ROWS, bool W8>
__device__ __forceinline__ void mfma_layer(
    char* pool, int inOff, int PKin, int outOff, int PKout,
    const h8v* __restrict__ wsB, const float* __restrict__ bias,
    const float* gpartL, float* sceL, const float* __restrict__ a3,
    int lane, int wid) {
  constexpr int NTP = (NT + 1) / 2;
  constexpr int MTL = ROWS / 16;   // exact: 80->5, 64->4
  const int r = lane & 15, g = lane >> 4;
  const char* Ain = pool + inOff;
  int wlo, mtb, mte;
  if constexpr (W8) {
    wlo = wid & 3;
    const int whi = wid >> 2;
    mtb = whi ? 3 : 0; mte = whi ? MTL : 3;
  } else { wlo = wid; mtb = 0; mte = MTL; }
  for (int p = wlo; p < NTP; p += 4) {
    const int nt0 = 2 * p;
    const bool two = (nt0 + 1 < NT);
    h8v wh0[KB], wl0[KB], wh1[KB], wl1[KB];
#pragma unroll
    for (int kb = 0; kb < KB; ++kb) {
      wh0[kb] = wsB[((kb * NT + nt0) * 2 + 0) * 64 + lane];
      wl0[kb] = wsB[((kb * NT + nt0) * 2 + 1) * 64 + lane];
      if (two) {
        wh1[kb] = wsB[((kb * NT + nt0 + 1) * 2 + 0) * 64 + lane];
        wl1[kb] = wsB[((kb * NT + nt0 + 1) * 2 + 1) * 64 + lane];
      }
    }
    for (int mt = mtb; mt < mte; ++mt) {
      f4 acc0 = {0.f, 0.f, 0.f, 0.f}, acc1 = {0.f, 0.f, 0.f, 0.f};
      const char* aP = Ain + (mt * 16 + r) * (PKin * 2) + g * 16;
#pragma unroll
      for (int kb = 0; kb < KB; ++kb) {
        h8v a = *(const h8v*)(aP + kb * 64);
        acc0 = __builtin_amdgcn_mfma_f32_16x16x32_f16(a, wh0[kb], acc0, 0, 0, 0);
        if (two) acc1 = __builtin_amdgcn_mfma_f32_16x16x32_f16(a, wh1[kb], acc1, 0, 0, 0);
        acc0 = __builtin_amdgcn_mfma_f32_16x16x32_f16(a, wl0[kb], acc0, 0, 0, 0);
        if (two) acc1 = __builtin_amdgcn_mfma_f32_16x16x32_f16(a, wl1[kb], acc1, 0, 0, 0);
      }
#pragma unroll
      for (int t = 0; t < 2; ++t) {
        if (t && !two) break;
        const int nt = nt0 + t;
        const f4 acc = t ? acc1 : acc0;
        const int col = nt * 16 + r;
        const int rbase = mt * 16 + g * 4;
        const float bcol = (col < C) ? bias[col] : 0.f;
        float gp = 0.f;
        if constexpr (MODE == 2) {
          if (col < C) gp = gpartL[(rbase / 20) * 100 + col];
        }
        float a3c = 0.f;
        if constexpr (MODE == 3) { if (col < C) a3c = a3[col]; }
#pragma unroll
        for (int q = 0; q < 4; ++q) {
          const int orow = rbase + q;
          float v = 0.f;
          if (col < C) {
            v = acc[q] + bcol;
            if constexpr (MODE == 2) v += gp;
            if constexpr (MODE != 1) v = fmaxf(v, 0.f);
          }
          if constexpr (MODE == 3) {
            float val = v * a3c;
            val += __shfl_xor(val, 1);
            val += __shfl_xor(val, 2);
            val += __shfl_xor(val, 4);
            val += __shfl_xor(val, 8);
            if (r == 0) atomicAdd(&sceL[orow], val);
          } else {
            ((ushort*)(pool + outOff))[orow * PKout + col] = f2h(v);
          }
        }
      }
    }
  }
}

// zero cols [112,128) of an f16 [ROWSZ][PK] buffer (epilogue covers [C,112))
template <int ROWSZ, int PK>
__device__ __forceinline__ void zero_tail(char* pool, int off, int tid) {
  if (tid < ROWSZ) {
    uint4* z = (uint4*)((ushort*)(pool + off) + (size_t)tid * PK + 112);
    z[0] = uint4{0, 0, 0, 0};
    z[1] = uint4{0, 0, 0, 0};
  }
}

// ---------------- kernel1: 4 batches per 512-thr WG ----------------
// (512,4): VGPR cap 64 (proven spill-free for this loop shape).
// LDS ~54.3KB -> 3 blocks/CU (162.8KB <= 160KB? 3*54272=162816 <= 163840 OK).
__global__ __launch_bounds__(NTHR, 4) void value_net_kernel(
    const float* __restrict__ state,
    const float* __restrict__ b1, const float* __restrict__ b2,
    const float* __restrict__ b3,
    const float* __restrict__ a1, const float* __restrict__ ab1,
    const float* __restrict__ ab2,
    const float* __restrict__ a3, const float* __restrict__ ab3,
    const uint4* __restrict__ ws, float* __restrict__ jointg) {
  __shared__ char pool[POOL1];
  __shared__ float gsL[NB * 100], gpartL[NB * 100], sceL[NROWSR], swL[NROWSR];

  const int tid = threadIdx.x;
  const int lane = tid & 63, wid = tid >> 6;
  const int b0 = blockIdx.x * NB;
  const h8v* wsb = (const h8v*)ws;

  // P0: stage state -> XS f16 (80 x PK40, cols 13..39 zero); zero sceL
  for (int i = tid; i < NROWSR * XS_PK; i += NTHR) {
    int row = i / XS_PK, k = i - row * XS_PK;
    float v = (k < 13) ? state[((size_t)b0 * 20 + row) * 13 + k] : 0.f;
    ((ushort*)(pool + XS_OFF))[row * XS_PK + k] = f2h(v);
  }
  if (tid < NROWSR) sceL[tid] = 0.f;
  __syncthreads();

  // P1: L1 13->150 relu  XS -> H1 (cols [150,160) zeroed by epilogue)
  mfma_layer<1, 10, 150, 0, NROWSR, true>(
      pool, XS_OFF, XS_PK, H1_OFF, H1_PK, wsb + L1B * 64, b1,
      nullptr, nullptr, nullptr, lane, wid);
  __syncthreads();

  // P2: zero H2 tail; L2 150->100 relu  H1 -> H2
  zero_tail<NROWSR, H2_PK>(pool, H2_OFF, tid);
  mfma_layer<5, 7, 100, 0, NROWSR, true>(
      pool, H1_OFF, H1_PK, H2_OFF, H2_PK, wsb + L2B * 64, b2,
      nullptr, nullptr, nullptr, lane, wid);
  __syncthreads();

  // P3: zero FEAT tail; L3 100->100 linear  H2 -> FEAT
  zero_tail<NROWSR, FEAT_PK>(pool, FEAT_OFF, tid);
  mfma_layer<4, 7, 100, 1, NROWSR, true>(
      pool, H2_OFF, H2_PK, FEAT_OFF, FEAT_PK, wsb + L3B * 64, b3,
      nullptr, nullptr, nullptr, lane, wid);
  __syncthreads();

  // P4: gs = mean over n (x0.05)
  if (tid < NB * 100) {
    const int b = tid / 100, d = tid - b * 100;
    const ushort* f = (const ushort*)(pool + FEAT_OFF);
    float s = 0.f;
    for (int n = 0; n < 20; ++n) s += h2f(f[(b * 20 + n) * FEAT_PK + d]);
    gsL[b * 100 + d] = s * 0.05f;
  }
  __syncthreads();

  // P5: gpart = gs @ a1[100:200]  (800 items, 2 passes)
  for (int it = tid; it < NB * 200; it += NTHR) {
    const int b = it / 200, rem = it - b * 200;
    const int j = rem >> 1, half = rem & 1;
    float acc = 0.f;
    const float* gsb = gsL + b * 100;
    for (int k = half * 50; k < half * 50 + 50; ++k)
      acc += gsb[k] * a1[(100 + k) * 100 + j];
    acc += __shfl_xor(acc, 1);
    if (half == 0) gpartL[b * 100 + j] = acc;
  }
  __syncthreads();

  // P6: A1 (feat half) + gpart, relu  FEAT -> S1 ([112,128) zeros inherited)
  mfma_layer<4, 7, 100, 2, NROWSR, true>(
      pool, FEAT_OFF, FEAT_PK, S1_OFF, S1_PK, wsb + A1B * 64, ab1,
      gpartL, nullptr, nullptr, lane, wid);
  __syncthreads();

  // P7: A2 relu + A3-dot fold -> sceL atomics
  mfma_layer<4, 7, 100, 3, NROWSR, true>(
      pool, S1_OFF, S1_PK, 0, 0, wsb + A2B * 64, ab2,
      nullptr, sceL, a3, lane, wid);
  __syncthreads();

  // P8: softmax over n of relu(score + ab3)
  if (tid < NROWSR) {
    const int b = tid / 20, n = tid - b * 20;
    const float ab3v = ab3[0];
    float m = -1e30f;
    for (int i = 0; i < 20; ++i) m = fmaxf(m, relu_f(sceL[b * 20 + i] + ab3v));
    float sum = 0.f, mine = 0.f;
    for (int i = 0; i < 20; ++i) {
      float e = __expf(relu_f(sceL[b * 20 + i] + ab3v) - m);
      sum += e;
      if (i == n) mine = e;
    }
    swL[tid] = mine / sum;
  }
  __syncthreads();

  // P9: weighted feature -> jointg (800 items); self (24 items)
  for (int it = tid; it < NB * 200; it += NTHR) {
    const int b = it / 200, rem = it - b * 200;
    const int d = rem >> 1, half = rem & 1;
    const ushort* f = (const ushort*)(pool + FEAT_OFF);
    float acc = 0.f;
    for (int n = half * 10; n < half * 10 + 10; ++n)
      acc += swL[b * 20 + n] * h2f(f[(b * 20 + n) * FEAT_PK + d]);
    acc += __shfl_xor(acc, 1);
    if (half == 0) jointg[(size_t)(b0 + b) * 106 + 6 + d] = acc;
  }
  if (tid < NB * 6) {
    const int b = tid / 6, i = tid - b * 6;
    jointg[(size_t)(b0 + b) * 106 + i] = state[((size_t)(b0 + b)) * 260 + i];
  }
}

// ---------------- kernel2: M-MLP GEMM over 16384 rows (f16) ----------------
__global__ __launch_bounds__(K2THR) void mlp2_kernel(
    const float* __restrict__ jointg,
    const float* __restrict__ mb1, const float* __restrict__ mb2,
    const float* __restrict__ mb3,
    const float* __restrict__ m4, const float* __restrict__ mb4,
    const uint4* __restrict__ ws, float* __restrict__ out) {
  __shared__ char pool[K2_POOL];
  __shared__ float m4L[100];
  const int tid = threadIdx.x, lane = tid & 63, wid = tid >> 6;
  const size_t r0 = (size_t)blockIdx.x * K2ROWS;
  const h8v* wsb = (const h8v*)ws;

  // stage joint -> f16 (PK=136, cols 106..135 zero); m4 -> LDS
  for (int i = tid; i < K2ROWS * 136; i += K2THR) {
    int row = i / 136, k = i - row * 136;
    float v = (k < 106) ? jointg[(r0 + row) * 106 + k] : 0.f;
    ((ushort*)(pool + K2_JT_OFF))[row * 136 + k] = f2h(v);
  }
  if (tid < 100) m4L[tid] = m4[tid];
  __syncthreads();

  // M1: 106->150 relu (jt PK136 -> v1 PK168)
  mfma_layer<4, 10, 150, 0, K2ROWS, false>(
      pool, K2_JT_OFF, 136, K2_V1_OFF, 168, wsb + M1B * 64, mb1,
      nullptr, nullptr, nullptr, lane, wid);
  __syncthreads();

  // M2: zero v2 tail; 150->100 relu (v1 -> v2 @0 PK136)
  zero_tail<K2ROWS, 136>(pool, 0, tid);
  mfma_layer<5, 7, 100, 0, K2ROWS, false>(
      pool, K2_V1_OFF, 168, 0, 136, wsb + M2B * 64, mb2,
      nullptr, nullptr, nullptr, lane, wid);
  __syncthreads();

  // M3: 100->100 relu (v2 -> v3 @V1_OFF PK136)
  mfma_layer<4, 7, 100, 0, K2ROWS, false>(
      pool, 0, 136, K2_V1_OFF, 136, wsb + M3B * 64, mb3,
      nullptr, nullptr, nullptr, lane, wid);
  __syncthreads();

  // M4: 100->1
  {
    const int row = tid >> 2, seg = tid & 3;
    const ushort* v3 = (const ushort*)(pool + K2_V1_OFF);
    float s = 0.f;
    for (int k = seg; k < 100; k += 4) s += h2f(v3[row * 136 + k]) * m4L[k];
    s += __shfl_xor(s, 1);
    s += __shfl_xor(s, 2);
    if (seg == 0) out[r0 + row] = s + mb4[0];
  }
}

extern "C" void kernel_launch(void* const* d_in, const int* in_sizes, int n_in,
                              void* d_out, int out_size, void* d_ws, size_t ws_size,
                              hipStream_t stream) {
  const float* state = (const float*)d_in[0];
  const float* w1 = (const float*)d_in[1];
  const float* b1 = (const float*)d_in[2];
  const float* w2 = (const float*)d_in[3];
  const float* b2 = (const float*)d_in[4];
  const float* w3 = (const float*)d_in[5];
  const float* b3 = (const float*)d_in[6];
  const float* a1 = (const float*)d_in[7];
  const float* ab1 = (const float*)d_in[8];
  const float* a2 = (const float*)d_in[9];
  const float* ab2 = (const float*)d_in[10];
  const float* a3 = (const float*)d_in[11];
  const float* ab3 = (const float*)d_in[12];
  const float* m1 = (const float*)d_in[13];
  const float* mb1 = (const float*)d_in[14];
  const float* m2 = (const float*)d_in[15];
  const float* mb2 = (const float*)d_in[16];
  const float* m3 = (const float*)d_in[17];
  const float* mb3 = (const float*)d_in[18];
  const float* m4 = (const float*)d_in[19];
  const float* mb4 = (const float*)d_in[20];
  float* out = (float*)d_out;
  uint4* ws = (uint4*)d_ws;
  float* jointg = (float*)d_ws + JOINT_F;

  prep_kernel<<<232, 64, 0, stream>>>(w1, w2, w3, a1, a2, m1, m2, m3, ws);

  const int B = in_sizes[0] / 260;  // 16384
  value_net_kernel<<<dim3(B / NB), dim3(NTHR), 0, stream>>>(
      state, b1, b2, b3, a1, ab1, ab2, a3, ab3, (const uint4*)ws, jointg);

  mlp2_kernel<<<dim3(B / K2ROWS), dim3(K2THR), 0, stream>>>(
      jointg, mb1, mb2, mb3, m4, mb4, (const uint4*)ws, out);
}

// Round 12
// 227.156 us; speedup vs baseline: 1.7767x; 1.1836x over previous
//
#include <hip/hip_runtime.h>
#include <math.h>

#define NTHR 512
#define NB 4              // batches per WG (kernel1)
#define NROWSR (NB * 20)  // 80 rows = 5 exact M-tiles

typedef _Float16 h8v __attribute__((ext_vector_type(8)));
using f4 = __attribute__((ext_vector_type(4))) float;

// kernel1 LDS pool (bytes). Single-plane f16: [rows][PK], 2B/elem.
// Row strides multiple of 16B: PK168->336B, PK136->272B, PK40->80B.
#define H1_OFF 0
#define H1_PK 168        // 80*168*2 = 26880
#define H2_OFF 26880
#define H2_PK 136        // 80*136*2 = 21760 -> end 48640
#define FEAT_OFF 0       // aliases H1 (dead after L2)
#define FEAT_PK 136
#define S1_OFF 26880     // aliases H2 (dead after L3); [112,128) zeros inherited
#define S1_PK 136
#define XS_OFF 26880     // aliases H2 region during P0/P1 only
#define XS_PK 40         // 80*40*2 = 6400
#define POOL1 48640

// ws fragment bases (1KB blocks; each (kb,nt) = 2 blocks hi+lo)
#define L1B 0
#define L2B 20
#define L3B 90
#define A1B 146
#define A2B 202
#define M1B 258
#define M2B 338
#define M3B 408
#define JOINT_F 118784   // float offset of joint[16384][106] in ws

// kernel2 (f16 single-plane)
#define K2ROWS 64
#define K2THR 256
#define K2_JT_OFF 0      // 64*136*2 = 17408
#define K2_V1_OFF 17408  // 64*168*2 = 21504 -> end 38912
#define K2_POOL 38912

__device__ __forceinline__ float relu_f(float v) { return fmaxf(v, 0.f); }
__device__ __forceinline__ float h2f(ushort u) {
  return (float)__builtin_bit_cast(_Float16, u);
}
__device__ __forceinline__ ushort f2h(float v) {
  return __builtin_bit_cast(ushort, (_Float16)v);
}

// ---------------- prep: pack hi/lo f16 weight B-fragments ----------------
// Frag (kb, nt, plane): lane l holds out-feature j = nt*16 + (l&15),
// k = kb*32 + (l>>4)*8 + e  (16B per lane).
__global__ __launch_bounds__(64) void prep_kernel(
    const float* __restrict__ w1, const float* __restrict__ w2,
    const float* __restrict__ w3, const float* __restrict__ a1,
    const float* __restrict__ a2, const float* __restrict__ m1,
    const float* __restrict__ m2, const float* __restrict__ m3,
    uint4* __restrict__ ws) {
  const int job = blockIdx.x;
  const int lane = threadIdx.x;
  const float* W;
  int K, C, NT, base, kb, nt, i;
  if (job < 10)       { W = w1; K = 13;  C = 150; NT = 10; base = L1B; kb = 0; nt = job; }
  else if (job < 45)  { W = w2; K = 150; C = 100; NT = 7;  base = L2B; i = job - 10;  kb = i / 7;  nt = i % 7; }
  else if (job < 73)  { W = w3; K = 100; C = 100; NT = 7;  base = L3B; i = job - 45;  kb = i / 7;  nt = i % 7; }
  else if (job < 101) { W = a1; K = 100; C = 100; NT = 7;  base = A1B; i = job - 73;  kb = i / 7;  nt = i % 7; }
  else if (job < 129) { W = a2; K = 100; C = 100; NT = 7;  base = A2B; i = job - 101; kb = i / 7;  nt = i % 7; }
  else if (job < 169) { W = m1; K = 106; C = 150; NT = 10; base = M1B; i = job - 129; kb = i / 10; nt = i % 10; }
  else if (job < 204) { W = m2; K = 150; C = 100; NT = 7;  base = M2B; i = job - 169; kb = i / 7;  nt = i % 7; }
  else                { W = m3; K = 100; C = 100; NT = 7;  base = M3B; i = job - 204; kb = i / 7;  nt = i % 7; }
  const int r = lane & 15, g = lane >> 4;
  const int j = nt * 16 + r;
  uint hi[8], lo[8];
  for (int e = 0; e < 8; ++e) {
    int k = kb * 32 + g * 8 + e;
    float v = (k < K && j < C) ? W[k * C + j] : 0.f;
    _Float16 hh = (_Float16)v;
    float hf = (float)hh;
    _Float16 ll = (_Float16)(v - hf);
    hi[e] = (uint)__builtin_bit_cast(ushort, hh);
    lo[e] = (uint)__builtin_bit_cast(ushort, ll);
  }
  uint4 vh = { hi[0] | (hi[1] << 16), hi[2] | (hi[3] << 16),
               hi[4] | (hi[5] << 16), hi[6] | (hi[7] << 16) };
  uint4 vl = { lo[0] | (lo[1] << 16), lo[2] | (lo[3] << 16),
               lo[4] | (lo[5] << 16), lo[6] | (lo[7] << 16) };
  ws[(size_t)(base + (kb * NT + nt) * 2 + 0) * 64 + lane] = vh;
  ws[(size_t)(base + (kb * NT + nt) * 2 + 1) * 64 + lane] = vl;
}

// ---------------- f16 MFMA dense layer, single-nt-per-wave (register diet) ----
// D-layout: col = lane&15 (+nt*16), act row = (lane>>4)*4+q (+mt*16).
// Live set: wh[KB]+wl[KB] (<=40 regs), 1 acc, 1 a-frag -> combined ~74 <= 84
// so __launch_bounds__(512,6) holds spill-free (R4's pair-preload did not).
// MODE: 0 relu->f16, 1 linear->f16, 2 relu+gpart->f16,
//       3 relu + a3-dot fold -> sceL atomics (no store)
// W8 (8 waves, MTL=5): wid&3 picks nt (stride 4), wid>>2 splits mt {0,1,2} vs {3,4}.
template <int KB, int NT, int C, int MODE, int ROWS, bool W8>
__device__ __forceinline__ void mfma_layer(
    char* pool, int inOff, int PKin, int outOff, int PKout,
    const h8v* __restrict__ wsB, const float* __restrict__ bias,
    const float* gpartL, float* sceL, const float* __restrict__ a3,
    int lane, int wid) {
  constexpr int MTL = ROWS / 16;   // exact: 80->5, 64->4
  const int r = lane & 15, g = lane >> 4;
  const char* Ain = pool + inOff;
  int wlo, mtb, mte;
  if constexpr (W8) {
    wlo = wid & 3;
    const int whi = wid >> 2;
    mtb = whi ? 3 : 0; mte = whi ? MTL : 3;
  } else { wlo = wid; mtb = 0; mte = MTL; }
  for (int nt = wlo; nt < NT; nt += 4) {
    h8v wh[KB], wl[KB];
#pragma unroll
    for (int kb = 0; kb < KB; ++kb) {
      wh[kb] = wsB[((kb * NT + nt) * 2 + 0) * 64 + lane];
      wl[kb] = wsB[((kb * NT + nt) * 2 + 1) * 64 + lane];
    }
    const int col = nt * 16 + r;
    const float bcol = (col < C) ? bias[col] : 0.f;
    float a3c = 0.f;
    if constexpr (MODE == 3) { if (col < C) a3c = a3[col]; }
    for (int mt = mtb; mt < mte; ++mt) {
      f4 acc = {0.f, 0.f, 0.f, 0.f};
      const char* aP = Ain + (mt * 16 + r) * (PKin * 2) + g * 16;
#pragma unroll
      for (int kb = 0; kb < KB; ++kb) {
        h8v a = *(const h8v*)(aP + kb * 64);
        acc = __builtin_amdgcn_mfma_f32_16x16x32_f16(a, wh[kb], acc, 0, 0, 0);
        acc = __builtin_amdgcn_mfma_f32_16x16x32_f16(a, wl[kb], acc, 0, 0, 0);
      }
      const int rbase = mt * 16 + g * 4;
      float gp = 0.f;
      if constexpr (MODE == 2) {
        if (col < C) gp = gpartL[(rbase / 20) * 100 + col];
      }
#pragma unroll
      for (int q = 0; q < 4; ++q) {
        const int orow = rbase + q;
        float v = 0.f;
        if (col < C) {
          v = acc[q] + bcol;
          if constexpr (MODE == 2) v += gp;
          if constexpr (MODE != 1) v = fmaxf(v, 0.f);
        }
        if constexpr (MODE == 3) {
          float val = v * a3c;
          val += __shfl_xor(val, 1);
          val += __shfl_xor(val, 2);
          val += __shfl_xor(val, 4);
          val += __shfl_xor(val, 8);
          if (r == 0) atomicAdd(&sceL[orow], val);
        } else {
          ((ushort*)(pool + outOff))[orow * PKout + col] = f2h(v);
        }
      }
    }
  }
}

// zero cols [112,128) of an f16 [ROWSZ][PK] buffer (epilogue covers [C,112))
template <int ROWSZ, int PK>
__device__ __forceinline__ void zero_tail(char* pool, int off, int tid) {
  if (tid < ROWSZ) {
    uint4* z = (uint4*)((ushort*)(pool + off) + (size_t)tid * PK + 112);
    z[0] = uint4{0, 0, 0, 0};
    z[1] = uint4{0, 0, 0, 0};
  }
}

// ---------------- kernel1: 4 batches per 512-thr WG ----------------
// (512,6): 6 waves/SIMD target -> combined VGPR+AGPR cap ~84.
// LDS 52.7KB incl. arrays -> 3 blocks/CU (158KB), 24 waves/CU.
__global__ __launch_bounds__(NTHR, 6) void value_net_kernel(
    const float* __restrict__ state,
    const float* __restrict__ b1, const float* __restrict__ b2,
    const float* __restrict__ b3,
    const float* __restrict__ a1, const float* __restrict__ ab1,
    const float* __restrict__ ab2,
    const float* __restrict__ a3, const float* __restrict__ ab3,
    const uint4* __restrict__ ws, float* __restrict__ jointg) {
  __shared__ char pool[POOL1];
  __shared__ float gsL[NB * 100], gpartL[NB * 100], sceL[NROWSR], swL[NROWSR];

  const int tid = threadIdx.x;
  const int lane = tid & 63, wid = tid >> 6;
  const int b0 = blockIdx.x * NB;
  const h8v* wsb = (const h8v*)ws;

  // P0: stage state -> XS f16 (80 x PK40, cols 13..39 zero); zero sceL
  for (int i = tid; i < NROWSR * XS_PK; i += NTHR) {
    int row = i / XS_PK, k = i - row * XS_PK;
    float v = (k < 13) ? state[((size_t)b0 * 20 + row) * 13 + k] : 0.f;
    ((ushort*)(pool + XS_OFF))[row * XS_PK + k] = f2h(v);
  }
  if (tid < NROWSR) sceL[tid] = 0.f;
  __syncthreads();

  // P1: L1 13->150 relu  XS -> H1 (cols [150,160) zeroed by epilogue)
  mfma_layer<1, 10, 150, 0, NROWSR, true>(
      pool, XS_OFF, XS_PK, H1_OFF, H1_PK, wsb + L1B * 64, b1,
      nullptr, nullptr, nullptr, lane, wid);
  __syncthreads();

  // P2: zero H2 tail; L2 150->100 relu  H1 -> H2
  zero_tail<NROWSR, H2_PK>(pool, H2_OFF, tid);
  mfma_layer<5, 7, 100, 0, NROWSR, true>(
      pool, H1_OFF, H1_PK, H2_OFF, H2_PK, wsb + L2B * 64, b2,
      nullptr, nullptr, nullptr, lane, wid);
  __syncthreads();

  // P3: zero FEAT tail; L3 100->100 linear  H2 -> FEAT
  zero_tail<NROWSR, FEAT_PK>(pool, FEAT_OFF, tid);
  mfma_layer<4, 7, 100, 1, NROWSR, true>(
      pool, H2_OFF, H2_PK, FEAT_OFF, FEAT_PK, wsb + L3B * 64, b3,
      nullptr, nullptr, nullptr, lane, wid);
  __syncthreads();

  // P4: gs = mean over n (x0.05)
  if (tid < NB * 100) {
    const int b = tid / 100, d = tid - b * 100;
    const ushort* f = (const ushort*)(pool + FEAT_OFF);
    float s = 0.f;
    for (int n = 0; n < 20; ++n) s += h2f(f[(b * 20 + n) * FEAT_PK + d]);
    gsL[b * 100 + d] = s * 0.05f;
  }
  __syncthreads();

  // P5: gpart = gs @ a1[100:200]  (800 items, 2 passes)
  for (int it = tid; it < NB * 200; it += NTHR) {
    const int b = it / 200, rem = it - b * 200;
    const int j = rem >> 1, half = rem & 1;
    float acc = 0.f;
    const float* gsb = gsL + b * 100;
    for (int k = half * 50; k < half * 50 + 50; ++k)
      acc += gsb[k] * a1[(100 + k) * 100 + j];
    acc += __shfl_xor(acc, 1);
    if (half == 0) gpartL[b * 100 + j] = acc;
  }
  __syncthreads();

  // P6: A1 (feat half) + gpart, relu  FEAT -> S1 ([112,128) zeros inherited)
  mfma_layer<4, 7, 100, 2, NROWSR, true>(
      pool, FEAT_OFF, FEAT_PK, S1_OFF, S1_PK, wsb + A1B * 64, ab1,
      gpartL, nullptr, nullptr, lane, wid);
  __syncthreads();

  // P7: A2 relu + A3-dot fold -> sceL atomics
  mfma_layer<4, 7, 100, 3, NROWSR, true>(
      pool, S1_OFF, S1_PK, 0, 0, wsb + A2B * 64, ab2,
      nullptr, sceL, a3, lane, wid);
  __syncthreads();

  // P8: softmax over n of relu(score + ab3)
  if (tid < NROWSR) {
    const int b = tid / 20, n = tid - b * 20;
    const float ab3v = ab3[0];
    float m = -1e30f;
    for (int i = 0; i < 20; ++i) m = fmaxf(m, relu_f(sceL[b * 20 + i] + ab3v));
    float sum = 0.f, mine = 0.f;
    for (int i = 0; i < 20; ++i) {
      float e = __expf(relu_f(sceL[b * 20 + i] + ab3v) - m);
      sum += e;
      if (i == n) mine = e;
    }
    swL[tid] = mine / sum;
  }
  __syncthreads();

  // P9: weighted feature -> jointg (800 items); self (24 items)
  for (int it = tid; it < NB * 200; it += NTHR) {
    const int b = it / 200, rem = it - b * 200;
    const int d = rem >> 1, half = rem & 1;
    const ushort* f = (const ushort*)(pool + FEAT_OFF);
    float acc = 0.f;
    for (int n = half * 10; n < half * 10 + 10; ++n)
      acc += swL[b * 20 + n] * h2f(f[(b * 20 + n) * FEAT_PK + d]);
    acc += __shfl_xor(acc, 1);
    if (half == 0) jointg[(size_t)(b0 + b) * 106 + 6 + d] = acc;
  }
  if (tid < NB * 6) {
    const int b = tid / 6, i = tid - b * 6;
    jointg[(size_t)(b0 + b) * 106 + i] = state[((size_t)(b0 + b)) * 260 + i];
  }
}

// ---------------- kernel2: M-MLP GEMM over 16384 rows (f16) ----------------
__global__ __launch_bounds__(K2THR) void mlp2_kernel(
    const float* __restrict__ jointg,
    const float* __restrict__ mb1, const float* __restrict__ mb2,
    const float* __restrict__ mb3,
    const float* __restrict__ m4, const float* __restrict__ mb4,
    const uint4* __restrict__ ws, float* __restrict__ out) {
  __shared__ char pool[K2_POOL];
  __shared__ float m4L[100];
  const int tid = threadIdx.x, lane = tid & 63, wid = tid >> 6;
  const size_t r0 = (size_t)blockIdx.x * K2ROWS;
  const h8v* wsb = (const h8v*)ws;

  // stage joint -> f16 (PK=136, cols 106..135 zero); m4 -> LDS
  for (int i = tid; i < K2ROWS * 136; i += K2THR) {
    int row = i / 136, k = i - row * 136;
    float v = (k < 106) ? jointg[(r0 + row) * 106 + k] : 0.f;
    ((ushort*)(pool + K2_JT_OFF))[row * 136 + k] = f2h(v);
  }
  if (tid < 100) m4L[tid] = m4[tid];
  __syncthreads();

  // M1: 106->150 relu (jt PK136 -> v1 PK168)
  mfma_layer<4, 10, 150, 0, K2ROWS, false>(
      pool, K2_JT_OFF, 136, K2_V1_OFF, 168, wsb + M1B * 64, mb1,
      nullptr, nullptr, nullptr, lane, wid);
  __syncthreads();

  // M2: zero v2 tail; 150->100 relu (v1 -> v2 @0 PK136)
  zero_tail<K2ROWS, 136>(pool, 0, tid);
  mfma_layer<5, 7, 100, 0, K2ROWS, false>(
      pool, K2_V1_OFF, 168, 0, 136, wsb + M2B * 64, mb2,
      nullptr, nullptr, nullptr, lane, wid);
  __syncthreads();

  // M3: 100->100 relu (v2 -> v3 @V1_OFF PK136)
  mfma_layer<4, 7, 100, 0, K2ROWS, false>(
      pool, 0, 136, K2_V1_OFF, 136, wsb + M3B * 64, mb3,
      nullptr, nullptr, nullptr, lane, wid);
  __syncthreads();

  // M4: 100->1
  {
    const int row = tid >> 2, seg = tid & 3;
    const ushort* v3 = (const ushort*)(pool + K2_V1_OFF);
    float s = 0.f;
    for (int k = seg; k < 100; k += 4) s += h2f(v3[row * 136 + k]) * m4L[k];
    s += __shfl_xor(s, 1);
    s += __shfl_xor(s, 2);
    if (seg == 0) out[r0 + row] = s + mb4[0];
  }
}

extern "C" void kernel_launch(void* const* d_in, const int* in_sizes, int n_in,
                              void* d_out, int out_size, void* d_ws, size_t ws_size,
                              hipStream_t stream) {
  const float* state = (const float*)d_in[0];
  const float* w1 = (const float*)d_in[1];
  const float* b1 = (const float*)d_in[2];
  const float* w2 = (const float*)d_in[3];
  const float* b2 = (const float*)d_in[4];
  const float* w3 = (const float*)d_in[5];
  const float* b3 = (const float*)d_in[6];
  const float* a1 = (const float*)d_in[7];
  const float* ab1 = (const float*)d_in[8];
  const float* a2 = (const float*)d_in[9];
  const float* ab2 = (const float*)d_in[10];
  const float* a3 = (const float*)d_in[11];
  const float* ab3 = (const float*)d_in[12];
  const float* m1 = (const float*)d_in[13];
  const float* mb1 = (const float*)d_in[14];
  const float* m2 = (const float*)d_in[15];
  const float* mb2 = (const float*)d_in[16];
  const float* m3 = (const float*)d_in[17];
  const float* mb3 = (const float*)d_in[18];
  const float* m4 = (const float*)d_in[19];
  const float* mb4 = (const float*)d_in[20];
  float* out = (float*)d_out;
  uint4* ws = (uint4*)d_ws;
  float* jointg = (float*)d_ws + JOINT_F;

  prep_kernel<<<232, 64, 0, stream>>>(w1, w2, w3, a1, a2, m1, m2, m3, ws);

  const int B = in_sizes[0] / 260;  // 16384
  value_net_kernel<<<dim3(B / NB), dim3(NTHR), 0, stream>>>(
      state, b1, b2, b3, a1, ab1, ab2, a3, ab3, (const uint4*)ws, jointg);

  mlp2_kernel<<<dim3(B / K2ROWS), dim3(K2THR), 0, stream>>>(
      jointg, mb1, mb2, mb3, m4, mb4, (const uint4*)ws, out);
}

// Round 13
// 220.184 us; speedup vs baseline: 1.8330x; 1.0317x over previous
//
#include <hip/hip_runtime.h>
#include <math.h>

#define NTHR 512
#define NB 4              // batches per WG (kernel1)
#define NROWSR (NB * 20)  // 80 rows = 5 exact M-tiles

typedef _Float16 h8v __attribute__((ext_vector_type(8)));
using f4 = __attribute__((ext_vector_type(4))) float;

// kernel1 LDS pool (bytes). Single-plane f16: [rows][PK], 2B/elem.
// Row strides multiple of 16B: PK168->336B, PK136->272B, PK40->80B.
#define H1_OFF 0
#define H1_PK 168        // 80*168*2 = 26880
#define H2_OFF 26880
#define H2_PK 136        // 80*136*2 = 21760 -> end 48640
#define FEAT_OFF 0       // aliases H1 (dead after L2)
#define FEAT_PK 136
#define S1_OFF 26880     // aliases H2 (dead after L3); [112,128) zeros inherited
#define S1_PK 136
#define XS_OFF 26880     // aliases H2 region during P0/P1 only
#define XS_PK 40         // 80*40*2 = 6400
#define POOL1 48640

// ws fragment bases (1KB blocks; each (kb,nt) = 2 blocks hi+lo)
#define L1B 0
#define L2B 20
#define L3B 90
#define A1B 146
#define A2B 202
#define M1B 258
#define M2B 338
#define M3B 408
#define JOINT_F 118784   // float offset of joint[16384][106] in ws

// kernel2 (f16 single-plane)
#define K2ROWS 64
#define K2THR 256
#define K2_JT_OFF 0      // 64*136*2 = 17408
#define K2_V1_OFF 17408  // 64*168*2 = 21504 -> end 38912
#define K2_POOL 38912

__device__ __forceinline__ float relu_f(float v) { return fmaxf(v, 0.f); }
__device__ __forceinline__ float h2f(ushort u) {
  return (float)__builtin_bit_cast(_Float16, u);
}
__device__ __forceinline__ ushort f2h(float v) {
  return __builtin_bit_cast(ushort, (_Float16)v);
}
__device__ __forceinline__ uint pk2h(float a, float b) {
  return (uint)f2h(a) | ((uint)f2h(b) << 16);
}

// guarded float4 from a C-element array at 4-aligned offset of4 (zeros beyond C)
__device__ __forceinline__ float4 load4_guard(const float* __restrict__ a, int of4, int C) {
  float4 v;
  if (of4 + 3 < C) v = *(const float4*)(a + of4);
  else {
    v.x = (of4 + 0 < C) ? a[of4 + 0] : 0.f;
    v.y = (of4 + 1 < C) ? a[of4 + 1] : 0.f;
    v.z = (of4 + 2 < C) ? a[of4 + 2] : 0.f;
    v.w = (of4 + 3 < C) ? a[of4 + 3] : 0.f;
  }
  return v;
}

// ---------------- prep: pack hi/lo f16 weight fragments ----------------
// Frag (kb, nt, plane): lane l holds out-feature j = nt*16 + (l&15),
// k = kb*32 + (l>>4)*8 + e  (16B per lane). Used as MFMA *A* operand.
__global__ __launch_bounds__(64) void prep_kernel(
    const float* __restrict__ w1, const float* __restrict__ w2,
    const float* __restrict__ w3, const float* __restrict__ a1,
    const float* __restrict__ a2, const float* __restrict__ m1,
    const float* __restrict__ m2, const float* __restrict__ m3,
    uint4* __restrict__ ws) {
  const int job = blockIdx.x;
  const int lane = threadIdx.x;
  const float* W;
  int K, C, NT, base, kb, nt, i;
  if (job < 10)       { W = w1; K = 13;  C = 150; NT = 10; base = L1B; kb = 0; nt = job; }
  else if (job < 45)  { W = w2; K = 150; C = 100; NT = 7;  base = L2B; i = job - 10;  kb = i / 7;  nt = i % 7; }
  else if (job < 73)  { W = w3; K = 100; C = 100; NT = 7;  base = L3B; i = job - 45;  kb = i / 7;  nt = i % 7; }
  else if (job < 101) { W = a1; K = 100; C = 100; NT = 7;  base = A1B; i = job - 73;  kb = i / 7;  nt = i % 7; }
  else if (job < 129) { W = a2; K = 100; C = 100; NT = 7;  base = A2B; i = job - 101; kb = i / 7;  nt = i % 7; }
  else if (job < 169) { W = m1; K = 106; C = 150; NT = 10; base = M1B; i = job - 129; kb = i / 10; nt = i % 10; }
  else if (job < 204) { W = m2; K = 150; C = 100; NT = 7;  base = M2B; i = job - 169; kb = i / 7;  nt = i % 7; }
  else                { W = m3; K = 100; C = 100; NT = 7;  base = M3B; i = job - 204; kb = i / 7;  nt = i % 7; }
  const int r = lane & 15, g = lane >> 4;
  const int j = nt * 16 + r;
  uint hi[8], lo[8];
  for (int e = 0; e < 8; ++e) {
    int k = kb * 32 + g * 8 + e;
    float v = (k < K && j < C) ? W[k * C + j] : 0.f;
    _Float16 hh = (_Float16)v;
    float hf = (float)hh;
    _Float16 ll = (_Float16)(v - hf);
    hi[e] = (uint)__builtin_bit_cast(ushort, hh);
    lo[e] = (uint)__builtin_bit_cast(ushort, ll);
  }
  uint4 vh = { hi[0] | (hi[1] << 16), hi[2] | (hi[3] << 16),
               hi[4] | (hi[5] << 16), hi[6] | (hi[7] << 16) };
  uint4 vl = { lo[0] | (lo[1] << 16), lo[2] | (lo[3] << 16),
               lo[4] | (lo[5] << 16), lo[6] | (lo[7] << 16) };
  ws[(size_t)(base + (kb * NT + nt) * 2 + 0) * 64 + lane] = vh;
  ws[(size_t)(base + (kb * NT + nt) * 2 + 1) * 64 + lane] = vl;
}

// ---------------- f16 MFMA dense layer, SWAPPED operands (W as A, act as B) ---
// D = W^T x act^T: D row = out-feature (lane>>4)*4+q (+nt*16),
//                  D col = act row lane&15 (+mt*16).
// Epilogue: lane holds 4 CONSECUTIVE out-features of ONE act row ->
// one packed ds_write_b64 per tile. Pad cols compute to exact 0.
// A/B fragment lane layouts are identical for 16x16x32, so ws packing and
// act ds_read pattern are unchanged from R12.
// MODE: 0 relu->f16, 1 linear->f16, 2 relu+gpart->f16,
//       3 relu + a3-dot fold -> sceL atomics (no store)
// W8 (8 waves, MTL=5): wid&3 picks nt (stride 4), wid>>2 splits mt {0,1,2} vs {3,4}.
template <int KB, int NT, int C, int MODE, int ROWS, bool W8>
__device__ __forceinline__ void mfma_layer(
    char* pool, int inOff, int PKin, int outOff, int PKout,
    const h8v* __restrict__ wsB, const float* __restrict__ bias,
    const float* gpartL, float* sceL, const float* __restrict__ a3,
    int lane, int wid) {
  constexpr int MTL = ROWS / 16;   // exact: 80->5, 64->4
  const int r = lane & 15, g = lane >> 4;
  const char* Ain = pool + inOff;
  int wlo, mtb, mte;
  if constexpr (W8) {
    wlo = wid & 3;
    const int whi = wid >> 2;
    mtb = whi ? 3 : 0; mte = whi ? MTL : 3;
  } else { wlo = wid; mtb = 0; mte = MTL; }
  for (int nt = wlo; nt < NT; nt += 4) {
    h8v wh[KB], wl[KB];
#pragma unroll
    for (int kb = 0; kb < KB; ++kb) {
      wh[kb] = wsB[((kb * NT + nt) * 2 + 0) * 64 + lane];
      wl[kb] = wsB[((kb * NT + nt) * 2 + 1) * 64 + lane];
    }
    const int of = nt * 16 + g * 4;          // 4 consecutive out-features
    const float4 b4 = load4_guard(bias, of, C);
    float4 a34 = {0.f, 0.f, 0.f, 0.f};
    if constexpr (MODE == 3) a34 = load4_guard(a3, of, C);
    for (int mt = mtb; mt < mte; ++mt) {
      const int ar = mt * 16 + r;            // act row
      f4 acc = {0.f, 0.f, 0.f, 0.f};
      const char* aP = Ain + ar * (PKin * 2) + g * 16;
#pragma unroll
      for (int kb = 0; kb < KB; ++kb) {
        h8v a = *(const h8v*)(aP + kb * 64);
        acc = __builtin_amdgcn_mfma_f32_16x16x32_f16(wh[kb], a, acc, 0, 0, 0);
        acc = __builtin_amdgcn_mfma_f32_16x16x32_f16(wl[kb], a, acc, 0, 0, 0);
      }
      float v0, v1, v2, v3;
      if constexpr (MODE == 2) {
        const float* gpb = gpartL + (ar / 20) * 100;
        float4 gp4 = (of + 3 < C) ? *(const float4*)(gpb + of)
                                  : load4_guard(gpb, of, C);
        v0 = acc[0] + b4.x + gp4.x; v1 = acc[1] + b4.y + gp4.y;
        v2 = acc[2] + b4.z + gp4.z; v3 = acc[3] + b4.w + gp4.w;
      } else {
        v0 = acc[0] + b4.x; v1 = acc[1] + b4.y;
        v2 = acc[2] + b4.z; v3 = acc[3] + b4.w;
      }
      if constexpr (MODE != 1) {
        v0 = fmaxf(v0, 0.f); v1 = fmaxf(v1, 0.f);
        v2 = fmaxf(v2, 0.f); v3 = fmaxf(v3, 0.f);
      }
      if constexpr (MODE == 3) {
        float val = v0 * a34.x + v1 * a34.y + v2 * a34.z + v3 * a34.w;
        val += __shfl_xor(val, 16);
        val += __shfl_xor(val, 32);
        if (lane < 16) atomicAdd(&sceL[ar], val);
      } else {
        uint2 pk = { pk2h(v0, v1), pk2h(v2, v3) };
        *(uint2*)((ushort*)(pool + outOff) + ar * PKout + of) = pk;
      }
    }
  }
}

// zero cols [112,128) of an f16 [ROWSZ][PK] buffer (epilogue covers [C,112))
template <int ROWSZ, int PK>
__device__ __forceinline__ void zero_tail(char* pool, int off, int tid) {
  if (tid < ROWSZ) {
    uint4* z = (uint4*)((ushort*)(pool + off) + (size_t)tid * PK + 112);
    z[0] = uint4{0, 0, 0, 0};
    z[1] = uint4{0, 0, 0, 0};
  }
}

// ---------------- kernel1: 4 batches per 512-thr WG ----------------
// (512,6): combined VGPR+AGPR cap ~84; live set ~64 -> spill-free.
// LDS 52.7KB -> 3 blocks/CU, 24 waves/CU.
__global__ __launch_bounds__(NTHR, 6) void value_net_kernel(
    const float* __restrict__ state,
    const float* __restrict__ b1, const float* __restrict__ b2,
    const float* __restrict__ b3,
    const float* __restrict__ a1, const float* __restrict__ ab1,
    const float* __restrict__ ab2,
    const float* __restrict__ a3, const float* __restrict__ ab3,
    const uint4* __restrict__ ws, float* __restrict__ jointg) {
  __shared__ char pool[POOL1];
  __shared__ float gsL[NB * 100], gpartL[NB * 100], sceL[NROWSR], swL[NROWSR];

  const int tid = threadIdx.x;
  const int lane = tid & 63, wid = tid >> 6;
  const int b0 = blockIdx.x * NB;
  const h8v* wsb = (const h8v*)ws;

  // P0: stage state -> XS f16 (80 x PK40, cols 13..39 zero); zero sceL
  for (int i = tid; i < NROWSR * XS_PK; i += NTHR) {
    int row = i / XS_PK, k = i - row * XS_PK;
    float v = (k < 13) ? state[((size_t)b0 * 20 + row) * 13 + k] : 0.f;
    ((ushort*)(pool + XS_OFF))[row * XS_PK + k] = f2h(v);
  }
  if (tid < NROWSR) sceL[tid] = 0.f;
  __syncthreads();

  // P1: L1 13->150 relu  XS -> H1 (cols [150,160) zeroed by epilogue)
  mfma_layer<1, 10, 150, 0, NROWSR, true>(
      pool, XS_OFF, XS_PK, H1_OFF, H1_PK, wsb + L1B * 64, b1,
      nullptr, nullptr, nullptr, lane, wid);
  __syncthreads();

  // P2: zero H2 tail; L2 150->100 relu  H1 -> H2
  zero_tail<NROWSR, H2_PK>(pool, H2_OFF, tid);
  mfma_layer<5, 7, 100, 0, NROWSR, true>(
      pool, H1_OFF, H1_PK, H2_OFF, H2_PK, wsb + L2B * 64, b2,
      nullptr, nullptr, nullptr, lane, wid);
  __syncthreads();

  // P3: zero FEAT tail; L3 100->100 linear  H2 -> FEAT
  zero_tail<NROWSR, FEAT_PK>(pool, FEAT_OFF, tid);
  mfma_layer<4, 7, 100, 1, NROWSR, true>(
      pool, H2_OFF, H2_PK, FEAT_OFF, FEAT_PK, wsb + L3B * 64, b3,
      nullptr, nullptr, nullptr, lane, wid);
  __syncthreads();

  // P4: gs = mean over n (x0.05)
  if (tid < NB * 100) {
    const int b = tid / 100, d = tid - b * 100;
    const ushort* f = (const ushort*)(pool + FEAT_OFF);
    float s = 0.f;
    for (int n = 0; n < 20; ++n) s += h2f(f[(b * 20 + n) * FEAT_PK + d]);
    gsL[b * 100 + d] = s * 0.05f;
  }
  __syncthreads();

  // P5: gpart = gs @ a1[100:200]  (800 items, 2 passes)
  for (int it = tid; it < NB * 200; it += NTHR) {
    const int b = it / 200, rem = it - b * 200;
    const int j = rem >> 1, half = rem & 1;
    float acc = 0.f;
    const float* gsb = gsL + b * 100;
    for (int k = half * 50; k < half * 50 + 50; ++k)
      acc += gsb[k] * a1[(100 + k) * 100 + j];
    acc += __shfl_xor(acc, 1);
    if (half == 0) gpartL[b * 100 + j] = acc;
  }
  __syncthreads();

  // P6: A1 (feat half) + gpart, relu  FEAT -> S1 ([112,128) zeros inherited)
  mfma_layer<4, 7, 100, 2, NROWSR, true>(
      pool, FEAT_OFF, FEAT_PK, S1_OFF, S1_PK, wsb + A1B * 64, ab1,
      gpartL, nullptr, nullptr, lane, wid);
  __syncthreads();

  // P7: A2 relu + A3-dot fold -> sceL atomics
  mfma_layer<4, 7, 100, 3, NROWSR, true>(
      pool, S1_OFF, S1_PK, 0, 0, wsb + A2B * 64, ab2,
      nullptr, sceL, a3, lane, wid);
  __syncthreads();

  // P8: softmax over n of relu(score + ab3)
  if (tid < NROWSR) {
    const int b = tid / 20, n = tid - b * 20;
    const float ab3v = ab3[0];
    float m = -1e30f;
    for (int i = 0; i < 20; ++i) m = fmaxf(m, relu_f(sceL[b * 20 + i] + ab3v));
    float sum = 0.f, mine = 0.f;
    for (int i = 0; i < 20; ++i) {
      float e = __expf(relu_f(sceL[b * 20 + i] + ab3v) - m);
      sum += e;
      if (i == n) mine = e;
    }
    swL[tid] = mine / sum;
  }
  __syncthreads();

  // P9: weighted feature -> jointg (800 items); self (24 items)
  for (int it = tid; it < NB * 200; it += NTHR) {
    const int b = it / 200, rem = it - b * 200;
    const int d = rem >> 1, half = rem & 1;
    const ushort* f = (const ushort*)(pool + FEAT_OFF);
    float acc = 0.f;
    for (int n = half * 10; n < half * 10 + 10; ++n)
      acc += swL[b * 20 + n] * h2f(f[(b * 20 + n) * FEAT_PK + d]);
    acc += __shfl_xor(acc, 1);
    if (half == 0) jointg[(size_t)(b0 + b) * 106 + 6 + d] = acc;
  }
  if (tid < NB * 6) {
    const int b = tid / 6, i = tid - b * 6;
    jointg[(size_t)(b0 + b) * 106 + i] = state[((size_t)(b0 + b)) * 260 + i];
  }
}

// ---------------- kernel2: M-MLP GEMM over 16384 rows (f16) ----------------
__global__ __launch_bounds__(K2THR) void mlp2_kernel(
    const float* __restrict__ jointg,
    const float* __restrict__ mb1, const float* __restrict__ mb2,
    const float* __restrict__ mb3,
    const float* __restrict__ m4, const float* __restrict__ mb4,
    const uint4* __restrict__ ws, float* __restrict__ out) {
  __shared__ char pool[K2_POOL];
  __shared__ float m4L[100];
  const int tid = threadIdx.x, lane = tid & 63, wid = tid >> 6;
  const size_t r0 = (size_t)blockIdx.x * K2ROWS;
  const h8v* wsb = (const h8v*)ws;

  // stage joint -> f16 (PK=136, cols 106..135 zero); m4 -> LDS
  for (int i = tid; i < K2ROWS * 136; i += K2THR) {
    int row = i / 136, k = i - row * 136;
    float v = (k < 106) ? jointg[(r0 + row) * 106 + k] : 0.f;
    ((ushort*)(pool + K2_JT_OFF))[row * 136 + k] = f2h(v);
  }
  if (tid < 100) m4L[tid] = m4[tid];
  __syncthreads();

  // M1: 106->150 relu (jt PK136 -> v1 PK168)
  mfma_layer<4, 10, 150, 0, K2ROWS, false>(
      pool, K2_JT_OFF, 136, K2_V1_OFF, 168, wsb + M1B * 64, mb1,
      nullptr, nullptr, nullptr, lane, wid);
  __syncthreads();

  // M2: zero v2 tail; 150->100 relu (v1 -> v2 @0 PK136)
  zero_tail<K2ROWS, 136>(pool, 0, tid);
  mfma_layer<5, 7, 100, 0, K2ROWS, false>(
      pool, K2_V1_OFF, 168, 0, 136, wsb + M2B * 64, mb2,
      nullptr, nullptr, nullptr, lane, wid);
  __syncthreads();

  // M3: 100->100 relu (v2 -> v3 @V1_OFF PK136)
  mfma_layer<4, 7, 100, 0, K2ROWS, false>(
      pool, 0, 136, K2_V1_OFF, 136, wsb + M3B * 64, mb3,
      nullptr, nullptr, nullptr, lane, wid);
  __syncthreads();

  // M4: 100->1
  {
    const int row = tid >> 2, seg = tid & 3;
    const ushort* v3 = (const ushort*)(pool + K2_V1_OFF);
    float s = 0.f;
    for (int k = seg; k < 100; k += 4) s += h2f(v3[row * 136 + k]) * m4L[k];
    s += __shfl_xor(s, 1);
    s += __shfl_xor(s, 2);
    if (seg == 0) out[r0 + row] = s + mb4[0];
  }
}

extern "C" void kernel_launch(void* const* d_in, const int* in_sizes, int n_in,
                              void* d_out, int out_size, void* d_ws, size_t ws_size,
                              hipStream_t stream) {
  const float* state = (const float*)d_in[0];
  const float* w1 = (const float*)d_in[1];
  const float* b1 = (const float*)d_in[2];
  const float* w2 = (const float*)d_in[3];
  const float* b2 = (const float*)d_in[4];
  const float* w3 = (const float*)d_in[5];
  const float* b3 = (const float*)d_in[6];
  const float* a1 = (const float*)d_in[7];
  const float* ab1 = (const float*)d_in[8];
  const float* a2 = (const float*)d_in[9];
  const float* ab2 = (const float*)d_in[10];
  const float* a3 = (const float*)d_in[11];
  const float* ab3 = (const float*)d_in[12];
  const float* m1 = (const float*)d_in[13];
  const float* mb1 = (const float*)d_in[14];
  const float* m2 = (const float*)d_in[15];
  const float* mb2 = (const float*)d_in[16];
  const float* m3 = (const float*)d_in[17];
  const float* mb3 = (const float*)d_in[18];
  const float* m4 = (const float*)d_in[19];
  const float* mb4 = (const float*)d_in[20];
  float* out = (float*)d_out;
  uint4* ws = (uint4*)d_ws;
  float* jointg = (float*)d_ws + JOINT_F;

  prep_kernel<<<232, 64, 0, stream>>>(w1, w2, w3, a1, a2, m1, m2, m3, ws);

  const int B = in_sizes[0] / 260;  // 16384
  value_net_kernel<<<dim3(B / NB), dim3(NTHR), 0, stream>>>(
      state, b1, b2, b3, a1, ab1, ab2, a3, ab3, (const uint4*)ws, jointg);

  mlp2_kernel<<<dim3(B / K2ROWS), dim3(K2THR), 0, stream>>>(
      jointg, mb1, mb2, mb3, m4, mb4, (const uint4*)ws, out);
}

// Round 14
// 162.865 us; speedup vs baseline: 2.4781x; 1.3519x over previous
//
#include <hip/hip_runtime.h>
#include <math.h>

#define NTHR 512
#define NB 4              // batches per WG (kernel1)
#define NROWSR (NB * 20)  // 80 rows = 5 exact M-tiles

typedef _Float16 h8v __attribute__((ext_vector_type(8)));
using f4 = __attribute__((ext_vector_type(4))) float;

// kernel1 LDS pool (bytes). Single-plane f16: [rows][PK], 2B/elem.
// Row strides multiple of 16B: PK168->336B, PK136->272B, PK40->80B.
#define H1_OFF 0
#define H1_PK 168        // 80*168*2 = 26880
#define H2_OFF 26880
#define H2_PK 136        // 80*136*2 = 21760 -> end 48640
#define FEAT_OFF 0       // aliases H1 (dead after L2)
#define FEAT_PK 136
#define S1_OFF 26880     // aliases H2 (dead after L3); [112,128) zeros inherited
#define S1_PK 136
#define XS_OFF 26880     // aliases H2 region during P0/P1 only
#define XS_PK 40         // 80*40*2 = 6400
#define GS_OFF S1_OFF    // GS16: 4 rows x PK136 f16, alive P4->P5 only (S1 rows 0-3)
#define POOL1 48640

// ws fragment bases (1KB blocks; each (kb,nt) = 2 blocks hi+lo)
#define L1B 0
#define L2B 20
#define L3B 90
#define A1B 146
#define A2B 202
#define M1B 258
#define M2B 338
#define M3B 408
#define A1GB 464         // a1 rows 100..199 (for gpart MFMA): 4kb x 7nt x 2
#define JOINT_F 133120   // float offset of joint[16384][106] in ws (after 520KB blocks)

// kernel2 (f16 single-plane)
#define K2ROWS 64
#define K2THR 256
#define K2_JT_OFF 0      // 64*136*2 = 17408
#define K2_V1_OFF 17408  // 64*168*2 = 21504 -> end 38912
#define K2_POOL 38912

__device__ __forceinline__ float relu_f(float v) { return fmaxf(v, 0.f); }
__device__ __forceinline__ float h2f(ushort u) {
  return (float)__builtin_bit_cast(_Float16, u);
}
__device__ __forceinline__ ushort f2h(float v) {
  return __builtin_bit_cast(ushort, (_Float16)v);
}
__device__ __forceinline__ uint pk2h(float a, float b) {
  return (uint)f2h(a) | ((uint)f2h(b) << 16);
}

// guarded float4 from a C-element array at 4-aligned offset of4 (zeros beyond C)
__device__ __forceinline__ float4 load4_guard(const float* __restrict__ a, int of4, int C) {
  float4 v;
  if (of4 + 3 < C) v = *(const float4*)(a + of4);
  else {
    v.x = (of4 + 0 < C) ? a[of4 + 0] : 0.f;
    v.y = (of4 + 1 < C) ? a[of4 + 1] : 0.f;
    v.z = (of4 + 2 < C) ? a[of4 + 2] : 0.f;
    v.w = (of4 + 3 < C) ? a[of4 + 3] : 0.f;
  }
  return v;
}

// ---------------- prep: pack hi/lo f16 weight fragments ----------------
// Frag (kb, nt, plane): lane l holds out-feature j = nt*16 + (l&15),
// k = kb*32 + (l>>4)*8 + e  (16B per lane). Used as MFMA *A* operand.
__global__ __launch_bounds__(64) void prep_kernel(
    const float* __restrict__ w1, const float* __restrict__ w2,
    const float* __restrict__ w3, const float* __restrict__ a1,
    const float* __restrict__ a2, const float* __restrict__ m1,
    const float* __restrict__ m2, const float* __restrict__ m3,
    uint4* __restrict__ ws) {
  const int job = blockIdx.x;
  const int lane = threadIdx.x;
  const float* W;
  int K, C, NT, base, kb, nt, i;
  if (job < 10)       { W = w1; K = 13;  C = 150; NT = 10; base = L1B; kb = 0; nt = job; }
  else if (job < 45)  { W = w2; K = 150; C = 100; NT = 7;  base = L2B; i = job - 10;  kb = i / 7;  nt = i % 7; }
  else if (job < 73)  { W = w3; K = 100; C = 100; NT = 7;  base = L3B; i = job - 45;  kb = i / 7;  nt = i % 7; }
  else if (job < 101) { W = a1; K = 100; C = 100; NT = 7;  base = A1B; i = job - 73;  kb = i / 7;  nt = i % 7; }
  else if (job < 129) { W = a2; K = 100; C = 100; NT = 7;  base = A2B; i = job - 101; kb = i / 7;  nt = i % 7; }
  else if (job < 169) { W = m1; K = 106; C = 150; NT = 10; base = M1B; i = job - 129; kb = i / 10; nt = i % 10; }
  else if (job < 204) { W = m2; K = 150; C = 100; NT = 7;  base = M2B; i = job - 169; kb = i / 7;  nt = i % 7; }
  else if (job < 232) { W = m3; K = 100; C = 100; NT = 7;  base = M3B; i = job - 204; kb = i / 7;  nt = i % 7; }
  else                { W = a1 + 10000; K = 100; C = 100; NT = 7; base = A1GB; i = job - 232; kb = i / 7; nt = i % 7; }
  const int r = lane & 15, g = lane >> 4;
  const int j = nt * 16 + r;
  uint hi[8], lo[8];
  for (int e = 0; e < 8; ++e) {
    int k = kb * 32 + g * 8 + e;
    float v = (k < K && j < C) ? W[k * C + j] : 0.f;
    _Float16 hh = (_Float16)v;
    float hf = (float)hh;
    _Float16 ll = (_Float16)(v - hf);
    hi[e] = (uint)__builtin_bit_cast(ushort, hh);
    lo[e] = (uint)__builtin_bit_cast(ushort, ll);
  }
  uint4 vh = { hi[0] | (hi[1] << 16), hi[2] | (hi[3] << 16),
               hi[4] | (hi[5] << 16), hi[6] | (hi[7] << 16) };
  uint4 vl = { lo[0] | (lo[1] << 16), lo[2] | (lo[3] << 16),
               lo[4] | (lo[5] << 16), lo[6] | (lo[7] << 16) };
  ws[(size_t)(base + (kb * NT + nt) * 2 + 0) * 64 + lane] = vh;
  ws[(size_t)(base + (kb * NT + nt) * 2 + 1) * 64 + lane] = vl;
}

// ---------------- f16 MFMA dense layer, SWAPPED operands (W as A, act as B) ---
// D = W^T x act^T: D row = out-feature (lane>>4)*4+q (+nt*16),
//                  D col = act row lane&15 (+mt*16).
// Epilogue: lane holds 4 CONSECUTIVE out-features of ONE act row ->
// one packed ds_write_b64 per tile. Pad cols compute to exact 0.
// MODE: 0 relu->f16, 1 linear->f16, 2 relu+gpart->f16,
//       3 relu + a3-dot fold -> sceL atomics (no store)
// W8 (8 waves, MTL=5): wid&3 picks nt (stride 4), wid>>2 splits mt {0,1,2} vs {3,4}.
template <int KB, int NT, int C, int MODE, int ROWS, bool W8>
__device__ __forceinline__ void mfma_layer(
    char* pool, int inOff, int PKin, int outOff, int PKout,
    const h8v* __restrict__ wsB, const float* __restrict__ bias,
    const float* gpartL, float* sceL, const float* __restrict__ a3,
    int lane, int wid) {
  constexpr int MTL = ROWS / 16;   // exact: 80->5, 64->4
  const int r = lane & 15, g = lane >> 4;
  const char* Ain = pool + inOff;
  int wlo, mtb, mte;
  if constexpr (W8) {
    wlo = wid & 3;
    const int whi = wid >> 2;
    mtb = whi ? 3 : 0; mte = whi ? MTL : 3;
  } else { wlo = wid; mtb = 0; mte = MTL; }
  for (int nt = wlo; nt < NT; nt += 4) {
    h8v wh[KB], wl[KB];
#pragma unroll
    for (int kb = 0; kb < KB; ++kb) {
      wh[kb] = wsB[((kb * NT + nt) * 2 + 0) * 64 + lane];
      wl[kb] = wsB[((kb * NT + nt) * 2 + 1) * 64 + lane];
    }
    const int of = nt * 16 + g * 4;          // 4 consecutive out-features
    const float4 b4 = load4_guard(bias, of, C);
    float4 a34 = {0.f, 0.f, 0.f, 0.f};
    if constexpr (MODE == 3) a34 = load4_guard(a3, of, C);
    for (int mt = mtb; mt < mte; ++mt) {
      const int ar = mt * 16 + r;            // act row
      f4 acc = {0.f, 0.f, 0.f, 0.f};
      const char* aP = Ain + ar * (PKin * 2) + g * 16;
#pragma unroll
      for (int kb = 0; kb < KB; ++kb) {
        h8v a = *(const h8v*)(aP + kb * 64);
        acc = __builtin_amdgcn_mfma_f32_16x16x32_f16(wh[kb], a, acc, 0, 0, 0);
        acc = __builtin_amdgcn_mfma_f32_16x16x32_f16(wl[kb], a, acc, 0, 0, 0);
      }
      float v0, v1, v2, v3;
      if constexpr (MODE == 2) {
        const float* gpb = gpartL + (ar / 20) * 100;
        float4 gp4 = (of + 3 < C) ? *(const float4*)(gpb + of)
                                  : load4_guard(gpb, of, C);
        v0 = acc[0] + b4.x + gp4.x; v1 = acc[1] + b4.y + gp4.y;
        v2 = acc[2] + b4.z + gp4.z; v3 = acc[3] + b4.w + gp4.w;
      } else {
        v0 = acc[0] + b4.x; v1 = acc[1] + b4.y;
        v2 = acc[2] + b4.z; v3 = acc[3] + b4.w;
      }
      if constexpr (MODE != 1) {
        v0 = fmaxf(v0, 0.f); v1 = fmaxf(v1, 0.f);
        v2 = fmaxf(v2, 0.f); v3 = fmaxf(v3, 0.f);
      }
      if constexpr (MODE == 3) {
        float val = v0 * a34.x + v1 * a34.y + v2 * a34.z + v3 * a34.w;
        val += __shfl_xor(val, 16);
        val += __shfl_xor(val, 32);
        if (lane < 16) atomicAdd(&sceL[ar], val);
      } else {
        uint2 pk = { pk2h(v0, v1), pk2h(v2, v3) };
        *(uint2*)((ushort*)(pool + outOff) + ar * PKout + of) = pk;
      }
    }
  }
}

// zero cols [112,128) of an f16 [ROWSZ][PK] buffer (epilogue covers [C,112))
template <int ROWSZ, int PK>
__device__ __forceinline__ void zero_tail(char* pool, int off, int tid) {
  if (tid < ROWSZ) {
    uint4* z = (uint4*)((ushort*)(pool + off) + (size_t)tid * PK + 112);
    z[0] = uint4{0, 0, 0, 0};
    z[1] = uint4{0, 0, 0, 0};
  }
}

// ---------------- kernel1: 4 batches per 512-thr WG ----------------
// (512,6): combined VGPR+AGPR cap ~84; live set ~64 -> spill-free.
// LDS ~51KB -> 3 blocks/CU, 24 waves/CU.
__global__ __launch_bounds__(NTHR, 6) void value_net_kernel(
    const float* __restrict__ state,
    const float* __restrict__ b1, const float* __restrict__ b2,
    const float* __restrict__ b3,
    const float* __restrict__ ab1, const float* __restrict__ ab2,
    const float* __restrict__ a3, const float* __restrict__ ab3,
    const uint4* __restrict__ ws, float* __restrict__ jointg) {
  __shared__ char pool[POOL1];
  __shared__ float gpartL[NB * 100], sceL[NROWSR], swL[NROWSR];

  const int tid = threadIdx.x;
  const int lane = tid & 63, wid = tid >> 6;
  const int b0 = blockIdx.x * NB;
  const h8v* wsb = (const h8v*)ws;

  // P0: stage state -> XS f16 (80 x PK40, cols 13..39 zero); zero sceL
  for (int i = tid; i < NROWSR * XS_PK; i += NTHR) {
    int row = i / XS_PK, k = i - row * XS_PK;
    float v = (k < 13) ? state[((size_t)b0 * 20 + row) * 13 + k] : 0.f;
    ((ushort*)(pool + XS_OFF))[row * XS_PK + k] = f2h(v);
  }
  if (tid < NROWSR) sceL[tid] = 0.f;
  __syncthreads();

  // P1: L1 13->150 relu  XS -> H1 (cols [150,160) zeroed by epilogue)
  mfma_layer<1, 10, 150, 0, NROWSR, true>(
      pool, XS_OFF, XS_PK, H1_OFF, H1_PK, wsb + L1B * 64, b1,
      nullptr, nullptr, nullptr, lane, wid);
  __syncthreads();

  // P2: zero H2 tail; L2 150->100 relu  H1 -> H2
  zero_tail<NROWSR, H2_PK>(pool, H2_OFF, tid);
  mfma_layer<5, 7, 100, 0, NROWSR, true>(
      pool, H1_OFF, H1_PK, H2_OFF, H2_PK, wsb + L2B * 64, b2,
      nullptr, nullptr, nullptr, lane, wid);
  __syncthreads();

  // P3: zero FEAT tail; L3 100->100 linear  H2 -> FEAT
  zero_tail<NROWSR, FEAT_PK>(pool, FEAT_OFF, tid);
  mfma_layer<4, 7, 100, 1, NROWSR, true>(
      pool, H2_OFF, H2_PK, FEAT_OFF, FEAT_PK, wsb + L3B * 64, b3,
      nullptr, nullptr, nullptr, lane, wid);
  __syncthreads();

  // P4: gs = mean over n (x0.05) -> GS16 f16 tile (4 rows, cols [100,128) zero)
  if (tid < NB * 100) {
    const int b = tid / 100, d = tid - b * 100;
    const ushort* f = (const ushort*)(pool + FEAT_OFF);
    float s = 0.f;
    for (int n = 0; n < 20; ++n) s += h2f(f[(b * 20 + n) * FEAT_PK + d]);
    ((ushort*)(pool + GS_OFF))[b * 136 + d] = f2h(s * 0.05f);
  } else if (tid < NB * 100 + NB * 28) {
    const int idx = tid - NB * 100;
    ((ushort*)(pool + GS_OFF))[(idx / 28) * 136 + 100 + (idx % 28)] = 0;
  }
  __syncthreads();

  // P5: gpart = gs @ a1[100:200] via MFMA (GS16 as B-operand, rows clamped r&3)
  if (wid < 7) {
    const int r = lane & 15, g = lane >> 4;
    const int nt = wid;
    const h8v* wsg = wsb + A1GB * 64;
    h8v wh[4], wl[4];
#pragma unroll
    for (int kb = 0; kb < 4; ++kb) {
      wh[kb] = wsg[((kb * 7 + nt) * 2 + 0) * 64 + lane];
      wl[kb] = wsg[((kb * 7 + nt) * 2 + 1) * 64 + lane];
    }
    const char* aP = pool + GS_OFF + (r & 3) * (136 * 2) + g * 16;
    f4 acc = {0.f, 0.f, 0.f, 0.f};
#pragma unroll
    for (int kb = 0; kb < 4; ++kb) {
      h8v a = *(const h8v*)(aP + kb * 64);
      acc = __builtin_amdgcn_mfma_f32_16x16x32_f16(wh[kb], a, acc, 0, 0, 0);
      acc = __builtin_amdgcn_mfma_f32_16x16x32_f16(wl[kb], a, acc, 0, 0, 0);
    }
    const int of = nt * 16 + g * 4;
    if (r < 4 && of < 100) {
      *(float4*)(&gpartL[r * 100 + of]) = float4{acc[0], acc[1], acc[2], acc[3]};
    }
  }
  __syncthreads();

  // P6: A1 (feat half) + gpart, relu  FEAT -> S1 ([112,128) zeros inherited)
  mfma_layer<4, 7, 100, 2, NROWSR, true>(
      pool, FEAT_OFF, FEAT_PK, S1_OFF, S1_PK, wsb + A1B * 64, ab1,
      gpartL, nullptr, nullptr, lane, wid);
  __syncthreads();

  // P7: A2 relu + A3-dot fold -> sceL atomics
  mfma_layer<4, 7, 100, 3, NROWSR, true>(
      pool, S1_OFF, S1_PK, 0, 0, wsb + A2B * 64, ab2,
      nullptr, sceL, a3, lane, wid);
  __syncthreads();

  // P8: softmax over n of relu(score + ab3)
  if (tid < NROWSR) {
    const int b = tid / 20, n = tid - b * 20;
    const float ab3v = ab3[0];
    float m = -1e30f;
    for (int i = 0; i < 20; ++i) m = fmaxf(m, relu_f(sceL[b * 20 + i] + ab3v));
    float sum = 0.f, mine = 0.f;
    for (int i = 0; i < 20; ++i) {
      float e = __expf(relu_f(sceL[b * 20 + i] + ab3v) - m);
      sum += e;
      if (i == n) mine = e;
    }
    swL[tid] = mine / sum;
  }
  __syncthreads();

  // P9: weighted feature -> jointg (800 items); self (24 items)
  for (int it = tid; it < NB * 200; it += NTHR) {
    const int b = it / 200, rem = it - b * 200;
    const int d = rem >> 1, half = rem & 1;
    const ushort* f = (const ushort*)(pool + FEAT_OFF);
    float acc = 0.f;
    for (int n = half * 10; n < half * 10 + 10; ++n)
      acc += swL[b * 20 + n] * h2f(f[(b * 20 + n) * FEAT_PK + d]);
    acc += __shfl_xor(acc, 1);
    if (half == 0) jointg[(size_t)(b0 + b) * 106 + 6 + d] = acc;
  }
  if (tid < NB * 6) {
    const int b = tid / 6, i = tid - b * 6;
    jointg[(size_t)(b0 + b) * 106 + i] = state[((size_t)(b0 + b)) * 260 + i];
  }
}

// ---------------- kernel2: M-MLP GEMM over 16384 rows (f16) ----------------
__global__ __launch_bounds__(K2THR) void mlp2_kernel(
    const float* __restrict__ jointg,
    const float* __restrict__ mb1, const float* __restrict__ mb2,
    const float* __restrict__ mb3,
    const float* __restrict__ m4, const float* __restrict__ mb4,
    const uint4* __restrict__ ws, float* __restrict__ out) {
  __shared__ char pool[K2_POOL];
  __shared__ float m4L[100];
  const int tid = threadIdx.x, lane = tid & 63, wid = tid >> 6;
  const size_t r0 = (size_t)blockIdx.x * K2ROWS;
  const h8v* wsb = (const h8v*)ws;

  // stage joint -> f16 (PK=136, cols 106..135 zero); m4 -> LDS
  for (int i = tid; i < K2ROWS * 136; i += K2THR) {
    int row = i / 136, k = i - row * 136;
    float v = (k < 106) ? jointg[(r0 + row) * 106 + k] : 0.f;
    ((ushort*)(pool + K2_JT_OFF))[row * 136 + k] = f2h(v);
  }
  if (tid < 100) m4L[tid] = m4[tid];
  __syncthreads();

  // M1: 106->150 relu (jt PK136 -> v1 PK168)
  mfma_layer<4, 10, 150, 0, K2ROWS, false>(
      pool, K2_JT_OFF, 136, K2_V1_OFF, 168, wsb + M1B * 64, mb1,
      nullptr, nullptr, nullptr, lane, wid);
  __syncthreads();

  // M2: zero v2 tail; 150->100 relu (v1 -> v2 @0 PK136)
  zero_tail<K2ROWS, 136>(pool, 0, tid);
  mfma_layer<5, 7, 100, 0, K2ROWS, false>(
      pool, K2_V1_OFF, 168, 0, 136, wsb + M2B * 64, mb2,
      nullptr, nullptr, nullptr, lane, wid);
  __syncthreads();

  // M3: 100->100 relu (v2 -> v3 @V1_OFF PK136)
  mfma_layer<4, 7, 100, 0, K2ROWS, false>(
      pool, 0, 136, K2_V1_OFF, 136, wsb + M3B * 64, mb3,
      nullptr, nullptr, nullptr, lane, wid);
  __syncthreads();

  // M4: 100->1
  {
    const int row = tid >> 2, seg = tid & 3;
    const ushort* v3 = (const ushort*)(pool + K2_V1_OFF);
    float s = 0.f;
    for (int k = seg; k < 100; k += 4) s += h2f(v3[row * 136 + k]) * m4L[k];
    s += __shfl_xor(s, 1);
    s += __shfl_xor(s, 2);
    if (seg == 0) out[r0 + row] = s + mb4[0];
  }
}

extern "C" void kernel_launch(void* const* d_in, const int* in_sizes, int n_in,
                              void* d_out, int out_size, void* d_ws, size_t ws_size,
                              hipStream_t stream) {
  const float* state = (const float*)d_in[0];
  const float* w1 = (const float*)d_in[1];
  const float* b1 = (const float*)d_in[2];
  const float* w2 = (const float*)d_in[3];
  const float* b2 = (const float*)d_in[4];
  const float* w3 = (const float*)d_in[5];
  const float* b3 = (const float*)d_in[6];
  const float* a1 = (const float*)d_in[7];
  const float* ab1 = (const float*)d_in[8];
  const float* a2 = (const float*)d_in[9];
  const float* ab2 = (const float*)d_in[10];
  const float* a3 = (const float*)d_in[11];
  const float* ab3 = (const float*)d_in[12];
  const float* m1 = (const float*)d_in[13];
  const float* mb1 = (const float*)d_in[14];
  const float* m2 = (const float*)d_in[15];
  const float* mb2 = (const float*)d_in[16];
  const float* m3 = (const float*)d_in[17];
  const float* mb3 = (const float*)d_in[18];
  const float* m4 = (const float*)d_in[19];
  const float* mb4 = (const float*)d_in[20];
  float* out = (float*)d_out;
  uint4* ws = (uint4*)d_ws;
  float* jointg = (float*)d_ws + JOINT_F;

  prep_kernel<<<260, 64, 0, stream>>>(w1, w2, w3, a1, a2, m1, m2, m3, ws);

  const int B = in_sizes[0] / 260;  // 16384
  value_net_kernel<<<dim3(B / NB), dim3(NTHR), 0, stream>>>(
      state, b1, b2, b3, ab1, ab2, a3, ab3, (const uint4*)ws, jointg);

  mlp2_kernel<<<dim3(B / K2ROWS), dim3(K2THR), 0, stream>>>(
      jointg, mb1, mb2, mb3, m4, mb4, (const uint4*)ws, out);
}

// Round 15
// 129.541 us; speedup vs baseline: 3.1156x; 1.2572x over previous
//
#include <hip/hip_runtime.h>
#include <math.h>

#define NTHR 512
#define NB 4              // batches per WG (kernel1)
#define NROWSR (NB * 20)  // 80 rows = 5 exact M-tiles

typedef _Float16 h8v __attribute__((ext_vector_type(8)));
using f4 = __attribute__((ext_vector_type(4))) float;

// kernel1 LDS pool (bytes). Single-plane f16: [rows][PK], 2B/elem.
// Row strides multiple of 16B: PK168->336B, PK136->272B, PK40->80B.
#define H1_OFF 0
#define H1_PK 168        // 80*168*2 = 26880
#define H2_OFF 26880
#define H2_PK 136        // 80*136*2 = 21760 -> end 48640
#define FEAT_OFF 0       // aliases H1 (dead after L2)
#define FEAT_PK 136
#define S1_OFF 26880     // aliases H2 (dead after L3); [112,128) zeros inherited
#define S1_PK 136
#define XS_OFF 26880     // aliases H2 region during P0/P1 only
#define XS_PK 40         // 80*40*2 = 6400
#define GS_OFF S1_OFF    // GS16: 4 rows x PK136 f16, alive P4->P5 only (S1 rows 0-3)
#define POOL1 48640

// ws fragment bases (1KB blocks; each (kb,nt) = 2 blocks hi+lo)
#define L1B 0
#define L2B 20
#define L3B 90
#define A1B 146
#define A2B 202
#define M1B 258
#define M2B 338
#define M3B 408
#define A1GB 464         // a1 rows 100..199 (for gpart MFMA): 4kb x 7nt x 2
#define JOINT_F 133120   // float offset of joint[16384][106] in ws (after 520KB blocks)

// kernel2 (f16 single-plane)
#define K2ROWS 64
#define K2THR 256
#define K2_JT_OFF 0      // 64*136*2 = 17408
#define K2_V1_OFF 17408  // 64*168*2 = 21504 -> end 38912
#define K2_POOL 38912

__device__ __forceinline__ float relu_f(float v) { return fmaxf(v, 0.f); }
__device__ __forceinline__ float h2f(ushort u) {
  return (float)__builtin_bit_cast(_Float16, u);
}
__device__ __forceinline__ ushort f2h(float v) {
  return __builtin_bit_cast(ushort, (_Float16)v);
}
__device__ __forceinline__ uint pk2h(float a, float b) {
  return (uint)f2h(a) | ((uint)f2h(b) << 16);
}

// guarded float4 from a C-element array at 4-aligned offset of4 (zeros beyond C)
__device__ __forceinline__ float4 load4_guard(const float* __restrict__ a, int of4, int C) {
  float4 v;
  if (of4 + 3 < C) v = *(const float4*)(a + of4);
  else {
    v.x = (of4 + 0 < C) ? a[of4 + 0] : 0.f;
    v.y = (of4 + 1 < C) ? a[of4 + 1] : 0.f;
    v.z = (of4 + 2 < C) ? a[of4 + 2] : 0.f;
    v.w = (of4 + 3 < C) ? a[of4 + 3] : 0.f;
  }
  return v;
}

// ---------------- prep: pack hi/lo f16 weight fragments ----------------
// Frag (kb, nt, plane): lane l holds out-feature j = nt*16 + (l&15),
// k = kb*32 + (l>>4)*8 + e  (16B per lane). Used as MFMA *A* operand.
__global__ __launch_bounds__(64) void prep_kernel(
    const float* __restrict__ w1, const float* __restrict__ w2,
    const float* __restrict__ w3, const float* __restrict__ a1,
    const float* __restrict__ a2, const float* __restrict__ m1,
    const float* __restrict__ m2, const float* __restrict__ m3,
    uint4* __restrict__ ws) {
  const int job = blockIdx.x;
  const int lane = threadIdx.x;
  const float* W;
  int K, C, NT, base, kb, nt, i;
  if (job < 10)       { W = w1; K = 13;  C = 150; NT = 10; base = L1B; kb = 0; nt = job; }
  else if (job < 45)  { W = w2; K = 150; C = 100; NT = 7;  base = L2B; i = job - 10;  kb = i / 7;  nt = i % 7; }
  else if (job < 73)  { W = w3; K = 100; C = 100; NT = 7;  base = L3B; i = job - 45;  kb = i / 7;  nt = i % 7; }
  else if (job < 101) { W = a1; K = 100; C = 100; NT = 7;  base = A1B; i = job - 73;  kb = i / 7;  nt = i % 7; }
  else if (job < 129) { W = a2; K = 100; C = 100; NT = 7;  base = A2B; i = job - 101; kb = i / 7;  nt = i % 7; }
  else if (job < 169) { W = m1; K = 106; C = 150; NT = 10; base = M1B; i = job - 129; kb = i / 10; nt = i % 10; }
  else if (job < 204) { W = m2; K = 150; C = 100; NT = 7;  base = M2B; i = job - 169; kb = i / 7;  nt = i % 7; }
  else if (job < 232) { W = m3; K = 100; C = 100; NT = 7;  base = M3B; i = job - 204; kb = i / 7;  nt = i % 7; }
  else                { W = a1 + 10000; K = 100; C = 100; NT = 7; base = A1GB; i = job - 232; kb = i / 7; nt = i % 7; }
  const int r = lane & 15, g = lane >> 4;
  const int j = nt * 16 + r;
  uint hi[8], lo[8];
  for (int e = 0; e < 8; ++e) {
    int k = kb * 32 + g * 8 + e;
    float v = (k < K && j < C) ? W[k * C + j] : 0.f;
    _Float16 hh = (_Float16)v;
    float hf = (float)hh;
    _Float16 ll = (_Float16)(v - hf);
    hi[e] = (uint)__builtin_bit_cast(ushort, hh);
    lo[e] = (uint)__builtin_bit_cast(ushort, ll);
  }
  uint4 vh = { hi[0] | (hi[1] << 16), hi[2] | (hi[3] << 16),
               hi[4] | (hi[5] << 16), hi[6] | (hi[7] << 16) };
  uint4 vl = { lo[0] | (lo[1] << 16), lo[2] | (lo[3] << 16),
               lo[4] | (lo[5] << 16), lo[6] | (lo[7] << 16) };
  ws[(size_t)(base + (kb * NT + nt) * 2 + 0) * 64 + lane] = vh;
  ws[(size_t)(base + (kb * NT + nt) * 2 + 1) * 64 + lane] = vl;
}

// ---------------- f16 MFMA dense layer, SWAPPED operands (W as A, act as B) ---
// D = W^T x act^T: D row = out-feature (lane>>4)*4+q (+nt*16),
//                  D col = act row lane&15 (+mt*16).
// Epilogue: lane holds 4 CONSECUTIVE out-features of ONE act row ->
// one packed ds_write_b64 per tile. Pad cols compute to exact 0.
// TERMS: 1 = single f16 weight term (kernel1), 2 = hi/lo compensated (kernel2).
// MODE: 0 relu->f16, 1 linear->f16, 2 relu+gpart->f16,
//       3 relu + a3-dot fold -> sceL atomics (no store)
// W8 (8 waves, MTL=5): wid&3 picks nt (stride 4), wid>>2 splits mt {0,1,2} vs {3,4}.
template <int KB, int NT, int C, int MODE, int ROWS, bool W8, int TERMS>
__device__ __forceinline__ void mfma_layer(
    char* pool, int inOff, int PKin, int outOff, int PKout,
    const h8v* __restrict__ wsB, const float* __restrict__ bias,
    const float* gpartL, float* sceL, const float* __restrict__ a3,
    int lane, int wid) {
  constexpr int MTL = ROWS / 16;   // exact: 80->5, 64->4
  const int r = lane & 15, g = lane >> 4;
  const char* Ain = pool + inOff;
  int wlo, mtb, mte;
  if constexpr (W8) {
    wlo = wid & 3;
    const int whi = wid >> 2;
    mtb = whi ? 3 : 0; mte = whi ? MTL : 3;
  } else { wlo = wid; mtb = 0; mte = MTL; }
  for (int nt = wlo; nt < NT; nt += 4) {
    h8v wh[KB], wl[KB];
#pragma unroll
    for (int kb = 0; kb < KB; ++kb) {
      wh[kb] = wsB[((kb * NT + nt) * 2 + 0) * 64 + lane];
      if constexpr (TERMS == 2)
        wl[kb] = wsB[((kb * NT + nt) * 2 + 1) * 64 + lane];
    }
    const int of = nt * 16 + g * 4;          // 4 consecutive out-features
    const float4 b4 = load4_guard(bias, of, C);
    float4 a34 = {0.f, 0.f, 0.f, 0.f};
    if constexpr (MODE == 3) a34 = load4_guard(a3, of, C);
    for (int mt = mtb; mt < mte; ++mt) {
      const int ar = mt * 16 + r;            // act row
      f4 acc = {0.f, 0.f, 0.f, 0.f};
      const char* aP = Ain + ar * (PKin * 2) + g * 16;
#pragma unroll
      for (int kb = 0; kb < KB; ++kb) {
        h8v a = *(const h8v*)(aP + kb * 64);
        acc = __builtin_amdgcn_mfma_f32_16x16x32_f16(wh[kb], a, acc, 0, 0, 0);
        if constexpr (TERMS == 2)
          acc = __builtin_amdgcn_mfma_f32_16x16x32_f16(wl[kb], a, acc, 0, 0, 0);
      }
      float v0, v1, v2, v3;
      if constexpr (MODE == 2) {
        const float* gpb = gpartL + (ar / 20) * 100;
        float4 gp4 = (of + 3 < C) ? *(const float4*)(gpb + of)
                                  : load4_guard(gpb, of, C);
        v0 = acc[0] + b4.x + gp4.x; v1 = acc[1] + b4.y + gp4.y;
        v2 = acc[2] + b4.z + gp4.z; v3 = acc[3] + b4.w + gp4.w;
      } else {
        v0 = acc[0] + b4.x; v1 = acc[1] + b4.y;
        v2 = acc[2] + b4.z; v3 = acc[3] + b4.w;
      }
      if constexpr (MODE != 1) {
        v0 = fmaxf(v0, 0.f); v1 = fmaxf(v1, 0.f);
        v2 = fmaxf(v2, 0.f); v3 = fmaxf(v3, 0.f);
      }
      if constexpr (MODE == 3) {
        float val = v0 * a34.x + v1 * a34.y + v2 * a34.z + v3 * a34.w;
        val += __shfl_xor(val, 16);
        val += __shfl_xor(val, 32);
        if (lane < 16) atomicAdd(&sceL[ar], val);
      } else {
        uint2 pk = { pk2h(v0, v1), pk2h(v2, v3) };
        *(uint2*)((ushort*)(pool + outOff) + ar * PKout + of) = pk;
      }
    }
  }
}

// zero cols [112,128) of an f16 [ROWSZ][PK] buffer (epilogue covers [C,112))
template <int ROWSZ, int PK>
__device__ __forceinline__ void zero_tail(char* pool, int off, int tid) {
  if (tid < ROWSZ) {
    uint4* z = (uint4*)((ushort*)(pool + off) + (size_t)tid * PK + 112);
    z[0] = uint4{0, 0, 0, 0};
    z[1] = uint4{0, 0, 0, 0};
  }
}

// ---------------- kernel1: 4 batches per 512-thr WG ----------------
// (512,6): combined VGPR+AGPR cap ~84; live set ~48 (TERMS=1) -> spill-free.
// LDS ~51KB -> 3 blocks/CU, 24 waves/CU.
__global__ __launch_bounds__(NTHR, 6) void value_net_kernel(
    const float* __restrict__ state,
    const float* __restrict__ b1, const float* __restrict__ b2,
    const float* __restrict__ b3,
    const float* __restrict__ ab1, const float* __restrict__ ab2,
    const float* __restrict__ a3, const float* __restrict__ ab3,
    const uint4* __restrict__ ws, float* __restrict__ jointg) {
  __shared__ char pool[POOL1];
  __shared__ float gpartL[NB * 100], sceL[NROWSR], swL[NROWSR];

  const int tid = threadIdx.x;
  const int lane = tid & 63, wid = tid >> 6;
  const int b0 = blockIdx.x * NB;
  const h8v* wsb = (const h8v*)ws;

  // P0: stage state -> XS f16 (80 x PK40, cols 13..39 zero); zero sceL
  for (int i = tid; i < NROWSR * XS_PK; i += NTHR) {
    int row = i / XS_PK, k = i - row * XS_PK;
    float v = (k < 13) ? state[((size_t)b0 * 20 + row) * 13 + k] : 0.f;
    ((ushort*)(pool + XS_OFF))[row * XS_PK + k] = f2h(v);
  }
  if (tid < NROWSR) sceL[tid] = 0.f;
  __syncthreads();

  // P1: L1 13->150 relu  XS -> H1 (cols [150,160) zeroed by epilogue)
  mfma_layer<1, 10, 150, 0, NROWSR, true, 1>(
      pool, XS_OFF, XS_PK, H1_OFF, H1_PK, wsb + L1B * 64, b1,
      nullptr, nullptr, nullptr, lane, wid);
  __syncthreads();

  // P2: zero H2 tail; L2 150->100 relu  H1 -> H2
  zero_tail<NROWSR, H2_PK>(pool, H2_OFF, tid);
  mfma_layer<5, 7, 100, 0, NROWSR, true, 1>(
      pool, H1_OFF, H1_PK, H2_OFF, H2_PK, wsb + L2B * 64, b2,
      nullptr, nullptr, nullptr, lane, wid);
  __syncthreads();

  // P3: zero FEAT tail; L3 100->100 linear  H2 -> FEAT
  zero_tail<NROWSR, FEAT_PK>(pool, FEAT_OFF, tid);
  mfma_layer<4, 7, 100, 1, NROWSR, true, 1>(
      pool, H2_OFF, H2_PK, FEAT_OFF, FEAT_PK, wsb + L3B * 64, b3,
      nullptr, nullptr, nullptr, lane, wid);
  __syncthreads();

  // P4: gs = mean over n (x0.05) -> GS16 f16 tile (4 rows, cols [100,128) zero)
  if (tid < NB * 100) {
    const int b = tid / 100, d = tid - b * 100;
    const ushort* f = (const ushort*)(pool + FEAT_OFF);
    float s = 0.f;
    for (int n = 0; n < 20; ++n) s += h2f(f[(b * 20 + n) * FEAT_PK + d]);
    ((ushort*)(pool + GS_OFF))[b * 136 + d] = f2h(s * 0.05f);
  } else if (tid < NB * 100 + NB * 28) {
    const int idx = tid - NB * 100;
    ((ushort*)(pool + GS_OFF))[(idx / 28) * 136 + 100 + (idx % 28)] = 0;
  }
  __syncthreads();

  // P5: gpart = gs @ a1[100:200] via MFMA (GS16 as B-operand, rows clamped r&3)
  if (wid < 7) {
    const int r = lane & 15, g = lane >> 4;
    const int nt = wid;
    const h8v* wsg = wsb + A1GB * 64;
    h8v wh[4];
#pragma unroll
    for (int kb = 0; kb < 4; ++kb)
      wh[kb] = wsg[((kb * 7 + nt) * 2 + 0) * 64 + lane];
    const char* aP = pool + GS_OFF + (r & 3) * (136 * 2) + g * 16;
    f4 acc = {0.f, 0.f, 0.f, 0.f};
#pragma unroll
    for (int kb = 0; kb < 4; ++kb) {
      h8v a = *(const h8v*)(aP + kb * 64);
      acc = __builtin_amdgcn_mfma_f32_16x16x32_f16(wh[kb], a, acc, 0, 0, 0);
    }
    const int of = nt * 16 + g * 4;
    if (r < 4 && of < 100) {
      *(float4*)(&gpartL[r * 100 + of]) = float4{acc[0], acc[1], acc[2], acc[3]};
    }
  }
  __syncthreads();

  // P6: A1 (feat half) + gpart, relu  FEAT -> S1 ([112,128) zeros inherited)
  mfma_layer<4, 7, 100, 2, NROWSR, true, 1>(
      pool, FEAT_OFF, FEAT_PK, S1_OFF, S1_PK, wsb + A1B * 64, ab1,
      gpartL, nullptr, nullptr, lane, wid);
  __syncthreads();

  // P7: A2 relu + A3-dot fold -> sceL atomics
  mfma_layer<4, 7, 100, 3, NROWSR, true, 1>(
      pool, S1_OFF, S1_PK, 0, 0, wsb + A2B * 64, ab2,
      nullptr, sceL, a3, lane, wid);
  __syncthreads();

  // P8: softmax over n of relu(score + ab3)
  if (tid < NROWSR) {
    const int b = tid / 20, n = tid - b * 20;
    const float ab3v = ab3[0];
    float m = -1e30f;
    for (int i = 0; i < 20; ++i) m = fmaxf(m, relu_f(sceL[b * 20 + i] + ab3v));
    float sum = 0.f, mine = 0.f;
    for (int i = 0; i < 20; ++i) {
      float e = __expf(relu_f(sceL[b * 20 + i] + ab3v) - m);
      sum += e;
      if (i == n) mine = e;
    }
    swL[tid] = mine / sum;
  }
  __syncthreads();

  // P9: weighted feature -> jointg (800 items); self (24 items)
  for (int it = tid; it < NB * 200; it += NTHR) {
    const int b = it / 200, rem = it - b * 200;
    const int d = rem >> 1, half = rem & 1;
    const ushort* f = (const ushort*)(pool + FEAT_OFF);
    float acc = 0.f;
    for (int n = half * 10; n < half * 10 + 10; ++n)
      acc += swL[b * 20 + n] * h2f(f[(b * 20 + n) * FEAT_PK + d]);
    acc += __shfl_xor(acc, 1);
    if (half == 0) jointg[(size_t)(b0 + b) * 106 + 6 + d] = acc;
  }
  if (tid < NB * 6) {
    const int b = tid / 6, i = tid - b * 6;
    jointg[(size_t)(b0 + b) * 106 + i] = state[((size_t)(b0 + b)) * 260 + i];
  }
}

// ---------------- kernel2: M-MLP GEMM over 16384 rows (f16, 2-term) ----------
__global__ __launch_bounds__(K2THR) void mlp2_kernel(
    const float* __restrict__ jointg,
    const float* __restrict__ mb1, const float* __restrict__ mb2,
    const float* __restrict__ mb3,
    const float* __restrict__ m4, const float* __restrict__ mb4,
    const uint4* __restrict__ ws, float* __restrict__ out) {
  __shared__ char pool[K2_POOL];
  __shared__ float m4L[100];
  const int tid = threadIdx.x, lane = tid & 63, wid = tid >> 6;
  const size_t r0 = (size_t)blockIdx.x * K2ROWS;
  const h8v* wsb = (const h8v*)ws;

  // stage joint -> f16 (PK=136, cols 106..135 zero); m4 -> LDS
  for (int i = tid; i < K2ROWS * 136; i += K2THR) {
    int row = i / 136, k = i - row * 136;
    float v = (k < 106) ? jointg[(r0 + row) * 106 + k] : 0.f;
    ((ushort*)(pool + K2_JT_OFF))[row * 136 + k] = f2h(v);
  }
  if (tid < 100) m4L[tid] = m4[tid];
  __syncthreads();

  // M1: 106->150 relu (jt PK136 -> v1 PK168)
  mfma_layer<4, 10, 150, 0, K2ROWS, false, 2>(
      pool, K2_JT_OFF, 136, K2_V1_OFF, 168, wsb + M1B * 64, mb1,
      nullptr, nullptr, nullptr, lane, wid);
  __syncthreads();

  // M2: zero v2 tail; 150->100 relu (v1 -> v2 @0 PK136)
  zero_tail<K2ROWS, 136>(pool, 0, tid);
  mfma_layer<5, 7, 100, 0, K2ROWS, false, 2>(
      pool, K2_V1_OFF, 168, 0, 136, wsb + M2B * 64, mb2,
      nullptr, nullptr, nullptr, lane, wid);
  __syncthreads();

  // M3: 100->100 relu (v2 -> v3 @V1_OFF PK136)
  mfma_layer<4, 7, 100, 0, K2ROWS, false, 2>(
      pool, 0, 136, K2_V1_OFF, 136, wsb + M3B * 64, mb3,
      nullptr, nullptr, nullptr, lane, wid);
  __syncthreads();

  // M4: 100->1
  {
    const int row = tid >> 2, seg = tid & 3;
    const ushort* v3 = (const ushort*)(pool + K2_V1_OFF);
    float s = 0.f;
    for (int k = seg; k < 100; k += 4) s += h2f(v3[row * 136 + k]) * m4L[k];
    s += __shfl_xor(s, 1);
    s += __shfl_xor(s, 2);
    if (seg == 0) out[r0 + row] = s + mb4[0];
  }
}

extern "C" void kernel_launch(void* const* d_in, const int* in_sizes, int n_in,
                              void* d_out, int out_size, void* d_ws, size_t ws_size,
                              hipStream_t stream) {
  const float* state = (const float*)d_in[0];
  const float* w1 = (const float*)d_in[1];
  const float* b1 = (const float*)d_in[2];
  const float* w2 = (const float*)d_in[3];
  const float* b2 = (const float*)d_in[4];
  const float* w3 = (const float*)d_in[5];
  const float* b3 = (const float*)d_in[6];
  const float* a1 = (const float*)d_in[7];
  const float* ab1 = (const float*)d_in[8];
  const float* a2 = (const float*)d_in[9];
  const float* ab2 = (const float*)d_in[10];
  const float* a3 = (const float*)d_in[11];
  const float* ab3 = (const float*)d_in[12];
  const float* m1 = (const float*)d_in[13];
  const float* mb1 = (const float*)d_in[14];
  const float* m2 = (const float*)d_in[15];
  const float* mb2 = (const float*)d_in[16];
  const float* m3 = (const float*)d_in[17];
  const float* mb3 = (const float*)d_in[18];
  const float* m4 = (const float*)d_in[19];
  const float* mb4 = (const float*)d_in[20];
  float* out = (float*)d_out;
  uint4* ws = (uint4*)d_ws;
  float* jointg = (float*)d_ws + JOINT_F;

  prep_kernel<<<260, 64, 0, stream>>>(w1, w2, w3, a1, a2, m1, m2, m3, ws);

  const int B = in_sizes[0] / 260;  // 16384
  value_net_kernel<<<dim3(B / NB), dim3(NTHR), 0, stream>>>(
      state, b1, b2, b3, ab1, ab2, a3, ab3, (const uint4*)ws, jointg);

  mlp2_kernel<<<dim3(B / K2ROWS), dim3(K2THR), 0, stream>>>(
      jointg, mb1, mb2, mb3, m4, mb4, (const uint4*)ws, out);
}

// Round 17
// 123.798 us; speedup vs baseline: 3.2601x; 1.0464x over previous
//
#include <hip/hip_runtime.h>
#include <math.h>

#define NTHR 512
#define NB 4              // batches per WG (kernel1)
#define NROWSR (NB * 20)  // 80 rows = 5 exact M-tiles

typedef _Float16 h8v __attribute__((ext_vector_type(8)));
typedef _Float16 h2v __attribute__((ext_vector_type(2)));
using f4 = __attribute__((ext_vector_type(4))) float;

__device__ __forceinline__ h2v cvt_pk_h2(float a, float b) {
  return __builtin_bit_cast(h2v, __builtin_amdgcn_cvt_pkrtz(a, b));
}

// kernel1 LDS pool (bytes). Single-plane f16: [rows][PK], 2B/elem.
#define H1_OFF 0
#define H1_PK 168        // 80*168*2 = 26880
#define H2_OFF 26880
#define H2_PK 136        // 80*136*2 = 21760 -> end 48640
#define FEAT_OFF 0       // aliases H1 (dead after L2)
#define FEAT_PK 136
#define S1_OFF 26880     // aliases H2 (dead after L3); [112,128) zeros inherited
#define S1_PK 136
#define XS_OFF 26880     // aliases H2 region during P0/P1 only
#define XS_PK 40         // 80*40*2 = 6400
#define GS_OFF S1_OFF    // GS16: 4 rows x PK136 f16, alive P4->P5 only
#define POOL1 48640

// ws fragment bases (1KB blocks; each (kb,nt) = 2 blocks hi+lo)
#define L1B 0
#define L2B 20
#define L3B 90
#define A1B 146
#define A2B 202
#define M1B 258
#define M2B 338
#define M3B 408
#define A1GB 464          // a1 rows 100..199 (gpart MFMA): 4kb x 7nt x 2
#define BIAS_BYTE 532480  // 520KB: packed f16 biases, 8 regions x 160 ushorts
#define JOINT_BYTE 536576 // f16 joint[16384][106]

// bias region offsets (ushorts)
#define BO_B1 0
#define BO_B2 160
#define BO_B3 320
#define BO_AB1 480
#define BO_MB1 800
#define BO_MB2 960
#define BO_MB3 1120

// kernel2 (f16 single-plane)
#define K2ROWS 64
#define K2THR 256
#define K2_JT_OFF 0      // 64*136*2 = 17408
#define K2_V1_OFF 17408  // 64*168*2 = 21504 -> end 38912
#define K2_POOL 38912

__device__ __forceinline__ float relu_f(float v) { return fmaxf(v, 0.f); }
__device__ __forceinline__ float h2f(ushort u) {
  return (float)__builtin_bit_cast(_Float16, u);
}
__device__ __forceinline__ ushort f2h(float v) {
  return __builtin_bit_cast(ushort, (_Float16)v);
}
__device__ __forceinline__ uint pk2h(float a, float b) {
  return (uint)f2h(a) | ((uint)f2h(b) << 16);
}

// guarded float4 (zeros beyond C)
__device__ __forceinline__ float4 load4_guard(const float* __restrict__ a, int of4, int C) {
  float4 v;
  if (of4 + 3 < C) v = *(const float4*)(a + of4);
  else {
    v.x = (of4 + 0 < C) ? a[of4 + 0] : 0.f;
    v.y = (of4 + 1 < C) ? a[of4 + 1] : 0.f;
    v.z = (of4 + 2 < C) ? a[of4 + 2] : 0.f;
    v.w = (of4 + 3 < C) ? a[of4 + 3] : 0.f;
  }
  return v;
}

// ---------------- prep: pack hi/lo f16 weight fragments + f16 biases ---------
__global__ __launch_bounds__(64) void prep_kernel(
    const float* __restrict__ w1, const float* __restrict__ w2,
    const float* __restrict__ w3, const float* __restrict__ a1,
    const float* __restrict__ a2, const float* __restrict__ m1,
    const float* __restrict__ m2, const float* __restrict__ m3,
    const float* __restrict__ b1, const float* __restrict__ b2,
    const float* __restrict__ b3, const float* __restrict__ ab1,
    const float* __restrict__ mb1, const float* __restrict__ mb2,
    const float* __restrict__ mb3,
    uint4* __restrict__ ws) {
  const int job = blockIdx.x;
  const int lane = threadIdx.x;
  if (job == 260) {  // pack biases -> f16 (zero-padded to 160 each)
    ushort* bh = (ushort*)((char*)ws + BIAS_BYTE);
    for (int idx = lane; idx < 1280; idx += 64) {
      const int reg = idx / 160, off = idx - reg * 160;
      const float* src = nullptr; int C = 0;
      switch (reg) {
        case 0: src = b1;  C = 150; break;
        case 1: src = b2;  C = 100; break;
        case 2: src = b3;  C = 100; break;
        case 3: src = ab1; C = 100; break;
        case 4: src = nullptr; C = 0; break;   // (spare)
        case 5: src = mb1; C = 150; break;
        case 6: src = mb2; C = 100; break;
        default: src = mb3; C = 100; break;
      }
      bh[idx] = (off < C) ? f2h(src[off]) : (ushort)0;
    }
    return;
  }
  const float* W;
  int K, C, NT, base, kb, nt, i;
  if (job < 10)       { W = w1; K = 13;  C = 150; NT = 10; base = L1B; kb = 0; nt = job; }
  else if (job < 45)  { W = w2; K = 150; C = 100; NT = 7;  base = L2B; i = job - 10;  kb = i / 7;  nt = i % 7; }
  else if (job < 73)  { W = w3; K = 100; C = 100; NT = 7;  base = L3B; i = job - 45;  kb = i / 7;  nt = i % 7; }
  else if (job < 101) { W = a1; K = 100; C = 100; NT = 7;  base = A1B; i = job - 73;  kb = i / 7;  nt = i % 7; }
  else if (job < 129) { W = a2; K = 100; C = 100; NT = 7;  base = A2B; i = job - 101; kb = i / 7;  nt = i % 7; }
  else if (job < 169) { W = m1; K = 106; C = 150; NT = 10; base = M1B; i = job - 129; kb = i / 10; nt = i % 10; }
  else if (job < 204) { W = m2; K = 150; C = 100; NT = 7;  base = M2B; i = job - 169; kb = i / 7;  nt = i % 7; }
  else if (job < 232) { W = m3; K = 100; C = 100; NT = 7;  base = M3B; i = job - 204; kb = i / 7;  nt = i % 7; }
  else                { W = a1 + 10000; K = 100; C = 100; NT = 7; base = A1GB; i = job - 232; kb = i / 7; nt = i % 7; }
  const int r = lane & 15, g = lane >> 4;
  const int j = nt * 16 + r;
  uint hi[8], lo[8];
  for (int e = 0; e < 8; ++e) {
    int k = kb * 32 + g * 8 + e;
    float v = (k < K && j < C) ? W[k * C + j] : 0.f;
    _Float16 hh = (_Float16)v;
    float hf = (float)hh;
    _Float16 ll = (_Float16)(v - hf);
    hi[e] = (uint)__builtin_bit_cast(ushort, hh);
    lo[e] = (uint)__builtin_bit_cast(ushort, ll);
  }
  uint4 vh = { hi[0] | (hi[1] << 16), hi[2] | (hi[3] << 16),
               hi[4] | (hi[5] << 16), hi[6] | (hi[7] << 16) };
  uint4 vl = { lo[0] | (lo[1] << 16), lo[2] | (lo[3] << 16),
               lo[4] | (lo[5] << 16), lo[6] | (lo[7] << 16) };
  ws[(size_t)(base + (kb * NT + nt) * 2 + 0) * 64 + lane] = vh;
  ws[(size_t)(base + (kb * NT + nt) * 2 + 1) * 64 + lane] = vl;
}

// ---------------- f16 MFMA dense layer, swapped operands, packed epilogue ----
// D = W^T x act^T: lane holds 4 consecutive out-features (of..of+3) of ONE
// act row. Packed-f16 epilogue: cvt_pkrtz + v_pk_add_f16 (bias/gpart f16) +
// v_pk_max_f16 + one ds_write_b64. Pad cols compute to exact 0.
// TERMS: 1 = single f16 weight term, 2 = hi/lo compensated.
// MODE: 0 relu->f16, 1 linear->f16, 2 relu+gpart->f16,
//       3 relu + a3-dot fold -> sceL atomics (f32 path, biasF)
template <int KB, int NT, int C, int MODE, int ROWS, bool W8, int TERMS>
__device__ __forceinline__ void mfma_layer(
    char* pool, int inOff, int PKin, int outOff, int PKout,
    const h8v* __restrict__ wsB, const ushort* __restrict__ biasH,
    const float* __restrict__ biasF, const ushort* gpartH, float* sceL,
    const float* __restrict__ a3, int lane, int wid) {
  constexpr int MTL = ROWS / 16;
  const int r = lane & 15, g = lane >> 4;
  const char* Ain = pool + inOff;
  int wlo, mtb, mte;
  if constexpr (W8) {
    wlo = wid & 3;
    const int whi = wid >> 2;
    mtb = whi ? 3 : 0; mte = whi ? MTL : 3;
  } else { wlo = wid; mtb = 0; mte = MTL; }
  for (int nt = wlo; nt < NT; nt += 4) {
    h8v wh[KB], wl[KB];
#pragma unroll
    for (int kb = 0; kb < KB; ++kb) {
      wh[kb] = wsB[((kb * NT + nt) * 2 + 0) * 64 + lane];
      if constexpr (TERMS == 2)
        wl[kb] = wsB[((kb * NT + nt) * 2 + 1) * 64 + lane];
    }
    const int of = nt * 16 + g * 4;          // 4 consecutive out-features
    uint2 bp;
    float4 b4, a34;
    if constexpr (MODE == 3) {
      b4 = load4_guard(biasF, of, C);
      a34 = load4_guard(a3, of, C);
    } else {
      bp = *(const uint2*)(biasH + of);
    }
    for (int mt = mtb; mt < mte; ++mt) {
      const int ar = mt * 16 + r;            // act row
      f4 acc = {0.f, 0.f, 0.f, 0.f};
      const char* aP = Ain + ar * (PKin * 2) + g * 16;
#pragma unroll
      for (int kb = 0; kb < KB; ++kb) {
        h8v a = *(const h8v*)(aP + kb * 64);
        acc = __builtin_amdgcn_mfma_f32_16x16x32_f16(wh[kb], a, acc, 0, 0, 0);
        if constexpr (TERMS == 2)
          acc = __builtin_amdgcn_mfma_f32_16x16x32_f16(wl[kb], a, acc, 0, 0, 0);
      }
      if constexpr (MODE == 3) {
        float v0 = fmaxf(acc[0] + b4.x, 0.f), v1 = fmaxf(acc[1] + b4.y, 0.f);
        float v2 = fmaxf(acc[2] + b4.z, 0.f), v3 = fmaxf(acc[3] + b4.w, 0.f);
        float val = v0 * a34.x + v1 * a34.y + v2 * a34.z + v3 * a34.w;
        val += __shfl_xor(val, 16);
        val += __shfl_xor(val, 32);
        if (lane < 16) atomicAdd(&sceL[ar], val);
      } else {
        h2v lo = cvt_pk_h2(acc[0], acc[1]);
        h2v hi = cvt_pk_h2(acc[2], acc[3]);
        lo += __builtin_bit_cast(h2v, bp.x);
        hi += __builtin_bit_cast(h2v, bp.y);
        if constexpr (MODE == 2) {
          uint2 gp = *(const uint2*)(gpartH + (ar / 20) * 112 + of);
          lo += __builtin_bit_cast(h2v, gp.x);
          hi += __builtin_bit_cast(h2v, gp.y);
        }
        if constexpr (MODE != 1) {
          h2v z = {(_Float16)0.f, (_Float16)0.f};
          lo = __builtin_elementwise_max(lo, z);
          hi = __builtin_elementwise_max(hi, z);
        }
        *(uint2*)((ushort*)(pool + outOff) + ar * PKout + of) =
            uint2{__builtin_bit_cast(uint, lo), __builtin_bit_cast(uint, hi)};
      }
    }
  }
}

// zero cols [112,128) of an f16 [ROWSZ][PK] buffer
template <int ROWSZ, int PK>
__device__ __forceinline__ void zero_tail(char* pool, int off, int tid) {
  if (tid < ROWSZ) {
    uint4* z = (uint4*)((ushort*)(pool + off) + (size_t)tid * PK + 112);
    z[0] = uint4{0, 0, 0, 0};
    z[1] = uint4{0, 0, 0, 0};
  }
}

// ---------------- kernel1: 4 batches per 512-thr WG ----------------
__global__ __launch_bounds__(NTHR, 6) void value_net_kernel(
    const float* __restrict__ state,
    const float* __restrict__ ab2,
    const float* __restrict__ a3, const float* __restrict__ ab3,
    const uint4* __restrict__ ws, ushort* __restrict__ jointgH) {
  __shared__ char pool[POOL1];
  __shared__ ushort gpartH[NB * 112];
  __shared__ float sceL[NROWSR], swL[NROWSR];

  const int tid = threadIdx.x;
  const int lane = tid & 63, wid = tid >> 6;
  const int b0 = blockIdx.x * NB;
  const h8v* wsb = (const h8v*)ws;
  const ushort* biasH = (const ushort*)((const char*)ws + BIAS_BYTE);

  // P0: stage state -> XS f16 (80 x PK40, cols 13..39 zero); zero sceL
  for (int i = tid; i < NROWSR * XS_PK; i += NTHR) {
    int row = i / XS_PK, k = i - row * XS_PK;
    float v = (k < 13) ? state[((size_t)b0 * 20 + row) * 13 + k] : 0.f;
    ((ushort*)(pool + XS_OFF))[row * XS_PK + k] = f2h(v);
  }
  if (tid < NROWSR) sceL[tid] = 0.f;
  __syncthreads();

  // P1: L1 13->150 relu  XS -> H1
  mfma_layer<1, 10, 150, 0, NROWSR, true, 1>(
      pool, XS_OFF, XS_PK, H1_OFF, H1_PK, wsb + L1B * 64, biasH + BO_B1,
      nullptr, nullptr, nullptr, nullptr, lane, wid);
  __syncthreads();

  // P2: zero H2 tail; L2 150->100 relu  H1 -> H2
  zero_tail<NROWSR, H2_PK>(pool, H2_OFF, tid);
  mfma_layer<5, 7, 100, 0, NROWSR, true, 1>(
      pool, H1_OFF, H1_PK, H2_OFF, H2_PK, wsb + L2B * 64, biasH + BO_B2,
      nullptr, nullptr, nullptr, nullptr, lane, wid);
  __syncthreads();

  // P3: zero FEAT tail; L3 100->100 linear  H2 -> FEAT
  zero_tail<NROWSR, FEAT_PK>(pool, FEAT_OFF, tid);
  mfma_layer<4, 7, 100, 1, NROWSR, true, 1>(
      pool, H2_OFF, H2_PK, FEAT_OFF, FEAT_PK, wsb + L3B * 64, biasH + BO_B3,
      nullptr, nullptr, nullptr, nullptr, lane, wid);
  __syncthreads();

  // P4: gs = mean over n (x0.05) -> GS16 f16 tile (cols [100,128) zero)
  if (tid < NB * 100) {
    const int b = tid / 100, d = tid - b * 100;
    const ushort* f = (const ushort*)(pool + FEAT_OFF);
    float s = 0.f;
    for (int n = 0; n < 20; ++n) s += h2f(f[(b * 20 + n) * FEAT_PK + d]);
    ((ushort*)(pool + GS_OFF))[b * 136 + d] = f2h(s * 0.05f);
  } else if (tid < NB * 100 + NB * 28) {
    const int idx = tid - NB * 100;
    ((ushort*)(pool + GS_OFF))[(idx / 28) * 136 + 100 + (idx % 28)] = 0;
  }
  __syncthreads();

  // P5: gpart = gs @ a1[100:200] via MFMA -> gpartH f16 (stride 112, pad 0)
  if (wid < 7) {
    const int r = lane & 15, g = lane >> 4;
    const int nt = wid;
    const h8v* wsg = wsb + A1GB * 64;
    h8v wh[4];
#pragma unroll
    for (int kb = 0; kb < 4; ++kb)
      wh[kb] = wsg[((kb * 7 + nt) * 2 + 0) * 64 + lane];
    const char* aP = pool + GS_OFF + (r & 3) * (136 * 2) + g * 16;
    f4 acc = {0.f, 0.f, 0.f, 0.f};
#pragma unroll
    for (int kb = 0; kb < 4; ++kb) {
      h8v a = *(const h8v*)(aP + kb * 64);
      acc = __builtin_amdgcn_mfma_f32_16x16x32_f16(wh[kb], a, acc, 0, 0, 0);
    }
    const int of = nt * 16 + g * 4;
    if (r < 4) {
      uint2 pk = { pk2h(acc[0], acc[1]), pk2h(acc[2], acc[3]) };
      *(uint2*)(gpartH + r * 112 + of) = pk;
    }
  }
  __syncthreads();

  // P6: A1 (feat half) + gpart, relu  FEAT -> S1
  mfma_layer<4, 7, 100, 2, NROWSR, true, 1>(
      pool, FEAT_OFF, FEAT_PK, S1_OFF, S1_PK, wsb + A1B * 64, biasH + BO_AB1,
      nullptr, gpartH, nullptr, nullptr, lane, wid);
  __syncthreads();

  // P7: A2 relu + A3-dot fold -> sceL atomics (f32 path)
  mfma_layer<4, 7, 100, 3, NROWSR, true, 1>(
      pool, S1_OFF, S1_PK, 0, 0, wsb + A2B * 64, nullptr,
      ab2, nullptr, sceL, a3, lane, wid);
  __syncthreads();

  // P8: softmax over n, wave-parallel (32-lane group per batch)
  if (tid < 128) {
    const int b = tid >> 5, l = tid & 31;
    const float ab3v = ab3[0];
    float s = (l < 20) ? relu_f(sceL[b * 20 + l] + ab3v) : -1e30f;
    float m = s;
#pragma unroll
    for (int d = 1; d < 32; d <<= 1) m = fmaxf(m, __shfl_xor(m, d));
    float e = (l < 20) ? __expf(s - m) : 0.f;
    float sum = e;
#pragma unroll
    for (int d = 1; d < 32; d <<= 1) sum += __shfl_xor(sum, d);
    if (l < 20) swL[b * 20 + l] = e / sum;
  }
  __syncthreads();

  // P9: weighted feature -> jointgH f16 (800 items); self (24 items)
  for (int it = tid; it < NB * 200; it += NTHR) {
    const int b = it / 200, rem = it - b * 200;
    const int d = rem >> 1, half = rem & 1;
    const ushort* f = (const ushort*)(pool + FEAT_OFF);
    float acc = 0.f;
    for (int n = half * 10; n < half * 10 + 10; ++n)
      acc += swL[b * 20 + n] * h2f(f[(b * 20 + n) * FEAT_PK + d]);
    acc += __shfl_xor(acc, 1);
    if (half == 0) jointgH[(size_t)(b0 + b) * 106 + 6 + d] = f2h(acc);
  }
  if (tid < NB * 6) {
    const int b = tid / 6, i = tid - b * 6;
    jointgH[(size_t)(b0 + b) * 106 + i] = f2h(state[((size_t)(b0 + b)) * 260 + i]);
  }
}

// ---------------- kernel2: M-MLP GEMM over 16384 rows (f16, 2-term) ----------
__global__ __launch_bounds__(K2THR) void mlp2_kernel(
    const ushort* __restrict__ jointgH,
    const float* __restrict__ m4, const float* __restrict__ mb4,
    const uint4* __restrict__ ws, float* __restrict__ out) {
  __shared__ char pool[K2_POOL];
  __shared__ float m4L[100];
  const int tid = threadIdx.x, lane = tid & 63, wid = tid >> 6;
  const size_t r0 = (size_t)blockIdx.x * K2ROWS;
  const h8v* wsb = (const h8v*)ws;
  const ushort* biasH = (const ushort*)((const char*)ws + BIAS_BYTE);

  // stage joint f16 -> LDS (PK=136, cols 106..135 zero); m4 -> LDS
  for (int i = tid; i < K2ROWS * 136; i += K2THR) {
    int row = i / 136, k = i - row * 136;
    ((ushort*)(pool + K2_JT_OFF))[row * 136 + k] =
        (k < 106) ? jointgH[(r0 + row) * 106 + k] : (ushort)0;
  }
  if (tid < 100) m4L[tid] = m4[tid];
  __syncthreads();

  // M1: 106->150 relu (jt PK136 -> v1 PK168)
  mfma_layer<4, 10, 150, 0, K2ROWS, false, 2>(
      pool, K2_JT_OFF, 136, K2_V1_OFF, 168, wsb + M1B * 64, biasH + BO_MB1,
      nullptr, nullptr, nullptr, nullptr, lane, wid);
  __syncthreads();

  // M2: zero v2 tail; 150->100 relu (v1 -> v2 @0 PK136)
  zero_tail<K2ROWS, 136>(pool, 0, tid);
  mfma_layer<5, 7, 100, 0, K2ROWS, false, 2>(
      pool, K2_V1_OFF, 168, 0, 136, wsb + M2B * 64, biasH + BO_MB2,
      nullptr, nullptr, nullptr, nullptr, lane, wid);
  __syncthreads();

  // M3: 100->100 relu (v2 -> v3 @V1_OFF PK136)
  mfma_layer<4, 7, 100, 0, K2ROWS, false, 2>(
      pool, 0, 136, K2_V1_OFF, 136, wsb + M3B * 64, biasH + BO_MB3,
      nullptr, nullptr, nullptr, nullptr, lane, wid);
  __syncthreads();

  // M4: 100->1
  {
    const int row = tid >> 2, seg = tid & 3;
    const ushort* v3 = (const ushort*)(pool + K2_V1_OFF);
    float s = 0.f;
    for (int k = seg; k < 100; k += 4) s += h2f(v3[row * 136 + k]) * m4L[k];
    s += __shfl_xor(s, 1);
    s += __shfl_xor(s, 2);
    if (seg == 0) out[r0 + row] = s + mb4[0];
  }
}

extern "C" void kernel_launch(void* const* d_in, const int* in_sizes, int n_in,
                              void* d_out, int out_size, void* d_ws, size_t ws_size,
                              hipStream_t stream) {
  const float* state = (const float*)d_in[0];
  const float* w1 = (const float*)d_in[1];
  const float* b1 = (const float*)d_in[2];
  const float* w2 = (const float*)d_in[3];
  const float* b2 = (const float*)d_in[4];
  const float* w3 = (const float*)d_in[5];
  const float* b3 = (const float*)d_in[6];
  const float* a1 = (const float*)d_in[7];
  const float* ab1 = (const float*)d_in[8];
  const float* a2 = (const float*)d_in[9];
  const float* ab2 = (const float*)d_in[10];
  const float* a3 = (const float*)d_in[11];
  const float* ab3 = (const float*)d_in[12];
  const float* m1 = (const float*)d_in[13];
  const float* mb1 = (const float*)d_in[14];
  const float* m2 = (const float*)d_in[15];
  const float* mb2 = (const float*)d_in[16];
  const float* m3 = (const float*)d_in[17];
  const float* mb3 = (const float*)d_in[18];
  const float* m4 = (const float*)d_in[19];
  const float* mb4 = (const float*)d_in[20];
  float* out = (float*)d_out;
  uint4* ws = (uint4*)d_ws;
  ushort* jointgH = (ushort*)((char*)d_ws + JOINT_BYTE);

  prep_kernel<<<261, 64, 0, stream>>>(w1, w2, w3, a1, a2, m1, m2, m3,
                                      b1, b2, b3, ab1, mb1, mb2, mb3, ws);

  const int B = in_sizes[0] / 260;  // 16384
  value_net_kernel<<<dim3(B / NB), dim3(NTHR), 0, stream>>>(
      state, ab2, a3, ab3, (const uint4*)ws, jointgH);

  mlp2_kernel<<<dim3(B / K2ROWS), dim3(K2THR), 0, stream>>>(
      jointgH, m4, mb4, (const uint4*)ws, out);
}